// Round 3
// baseline (1273.345 us; speedup 1.0000x reference)
//
#include <hip/hip_runtime.h>
#include <hip/hip_bf16.h>

#define DEVINL __device__ __forceinline__

constexpr int N_NODES = 50000;
constexpr int N_EDGES = 800000;
constexpr int ET      = N_EDGES + N_NODES;   // edges + self loops
constexpr int F_IN    = 256;
constexpr int H       = 96;
constexpr int NG      = 64;                  // graphs
constexpr float BN_EPS = 1e-5f;

DEVINL float bf2f(unsigned int u) {
    union { unsigned int i; float f; } c; c.i = u << 16; return c.f;
}
DEVINL unsigned short f2bf(float f) {
    union { float f; unsigned int i; } c; c.f = f;
    unsigned int x = c.i;
    return (unsigned short)((x + 0x7fffu + ((x >> 16) & 1u)) >> 16);
}
DEVINL float lrelu01(float v) { return v >= 0.f ? v : 0.01f * v; }
// dtype-flag aware scalar load of a "float tensor" input
DEVINL float ldf(const void* p, size_t i, int f32) {
    return f32 ? ((const float*)p)[i] : bf2f(((const unsigned short*)p)[i]);
}

// ---------------------------------------------------------------------------
// dtype detection: interpret first 64 shorts of x as bf16. fp32-backed data
// has random mantissa shorts -> many |v|>1e4/NaN. bf16-backed -> none.
// ---------------------------------------------------------------------------
__global__ void detect_k(const unsigned short* __restrict__ x, int* __restrict__ flag)
{
    int l = threadIdx.x;
    float f = bf2f(x[l]);
    bool huge = !(fabsf(f) <= 1e4f);          // catches NaN/Inf too
    unsigned long long m = __ballot(huge);
    if (l == 0) flag[0] = (__popcll(m) >= 8) ? 1 : 0;   // 1 = fp32, 0 = bf16
}

// ---------------------------------------------------------------------------
// GEMM: out[M,96] = A[M,K] @ W[K,96]  (A,W per dflag; out bf16; fp32 accum)
// EPI: 0 = plain, 1 = lrelu(acc+bias), 2 = lrelu(acc+bias) -> out and out2
// AWS: 1 if A lives in workspace (always bf16), 0 if A is an input (per dflag)
// ---------------------------------------------------------------------------
template<int EPI, int AWS>
__global__ __launch_bounds__(256) void gemm_k(
    const void* __restrict__ Ap, const void* __restrict__ Wp,
    const void* __restrict__ bp, const int* __restrict__ dflag,
    unsigned short* __restrict__ out, unsigned short* __restrict__ out2,
    int M, int K)
{
    __shared__ float As[64][36];
    __shared__ float Ws[32][96];
    const int f32  = AWS ? 0 : dflag[0];
    const int wf32 = dflag[0];
    const int tid  = threadIdx.x;
    const int row0 = blockIdx.x * 64;
    const int tm0  = (tid >> 4) << 2;   // 0..60
    const int tn0  = (tid & 15) * 6;    // 0..90
    const int lm   = tid >> 2;          // load row 0..63
    const int lk   = (tid & 3) << 3;    // 0,8,16,24
    const int lr   = row0 + lm;

    float acc[4][6] = {};

    for (int kc = 0; kc < K; kc += 32) {
        if (lr < M) {
            if (f32) {
                const float* A = (const float*)Ap;
                const float4* p = (const float4*)(A + (size_t)lr * K + kc + lk);
                float4 v0 = p[0], v1 = p[1];
                *(float4*)&As[lm][lk]     = v0;
                *(float4*)&As[lm][lk + 4] = v1;
            } else {
                const unsigned short* A = (const unsigned short*)Ap;
                uint4 u = *(const uint4*)(A + (size_t)lr * K + kc + lk);
                *(float4*)&As[lm][lk]     = make_float4(bf2f(u.x & 0xffff), bf2f(u.x >> 16),
                                                        bf2f(u.y & 0xffff), bf2f(u.y >> 16));
                *(float4*)&As[lm][lk + 4] = make_float4(bf2f(u.z & 0xffff), bf2f(u.z >> 16),
                                                        bf2f(u.w & 0xffff), bf2f(u.w >> 16));
            }
        } else {
            *(float4*)&As[lm][lk]     = make_float4(0.f, 0.f, 0.f, 0.f);
            *(float4*)&As[lm][lk + 4] = make_float4(0.f, 0.f, 0.f, 0.f);
        }

        #pragma unroll
        for (int p = 0; p < 3; p++) {
            int f = p * 1024 + tid * 4;
            int k = f / 96, j = f - k * 96;   // j is a multiple of 4
            if (wf32) {
                const float* W = (const float*)Wp;
                *(float4*)&Ws[k][j] = *(const float4*)(W + (size_t)(kc + k) * 96 + j);
            } else {
                const unsigned short* W = (const unsigned short*)Wp;
                uint2 u = *(const uint2*)(W + (size_t)(kc + k) * 96 + j);
                *(float4*)&Ws[k][j] = make_float4(bf2f(u.x & 0xffff), bf2f(u.x >> 16),
                                                  bf2f(u.y & 0xffff), bf2f(u.y >> 16));
            }
        }
        __syncthreads();

        #pragma unroll
        for (int kk = 0; kk < 32; kk++) {
            float aa[4];
            aa[0] = As[tm0 + 0][kk]; aa[1] = As[tm0 + 1][kk];
            aa[2] = As[tm0 + 2][kk]; aa[3] = As[tm0 + 3][kk];
            const float2* wp2 = (const float2*)&Ws[kk][tn0];
            float2 w01 = wp2[0], w23 = wp2[1], w45 = wp2[2];
            float wv[6] = { w01.x, w01.y, w23.x, w23.y, w45.x, w45.y };
            #pragma unroll
            for (int i = 0; i < 4; i++)
                #pragma unroll
                for (int j = 0; j < 6; j++)
                    acc[i][j] = fmaf(aa[i], wv[j], acc[i][j]);
        }
        __syncthreads();
    }

    float bv[6];
    if (EPI > 0) {
        #pragma unroll
        for (int j = 0; j < 6; j++) bv[j] = ldf(bp, tn0 + j, wf32);
    }
    #pragma unroll
    for (int i = 0; i < 4; i++) {
        int r = row0 + tm0 + i;
        if (r >= M) continue;
        size_t o = (size_t)r * 96 + tn0;   // even -> 4B-aligned bf16 addr
        unsigned int pk[3];
        #pragma unroll
        for (int j = 0; j < 3; j++) {
            float v0 = acc[i][2 * j], v1 = acc[i][2 * j + 1];
            if (EPI > 0) {
                v0 = lrelu01(v0 + bv[2 * j]);
                v1 = lrelu01(v1 + bv[2 * j + 1]);
            }
            pk[j] = (unsigned int)f2bf(v0) | ((unsigned int)f2bf(v1) << 16);
        }
        unsigned int* po = (unsigned int*)(out + o);
        po[0] = pk[0]; po[1] = pk[1]; po[2] = pk[2];
        if (EPI == 2) {
            unsigned int* po2 = (unsigned int*)(out2 + o);
            po2[0] = pk[0]; po2[1] = pk[1]; po2[2] = pk[2];
        }
    }
}

// ---------------------------------------------------------------------------
// Per-node attention scalars: s[v] = h2[v]·a_s, d[v] = h2[v]·a_d (wave/node)
// ---------------------------------------------------------------------------
__global__ __launch_bounds__(256) void sd_k(
    const unsigned short* __restrict__ h2, const void* __restrict__ as_,
    const void* __restrict__ ad_, const int* __restrict__ dflag,
    float* __restrict__ s, float* __restrict__ d, int M)
{
    int f32 = dflag[0];
    int v = (blockIdx.x * blockDim.x + threadIdx.x) >> 6;
    int l = threadIdx.x & 63;
    if (v >= M) return;
    const unsigned short* r = h2 + (size_t)v * 96;
    float x1 = bf2f(r[l]);
    float x2 = (l < 32) ? bf2f(r[64 + l]) : 0.f;
    float as1 = ldf(as_, l, f32),  ad1 = ldf(ad_, l, f32);
    float as2 = (l < 32) ? ldf(as_, 64 + l, f32) : 0.f;
    float ad2 = (l < 32) ? ldf(ad_, 64 + l, f32) : 0.f;
    float ps = x1 * as1 + x2 * as2;
    float pd = x1 * ad1 + x2 * ad2;
    #pragma unroll
    for (int off = 32; off > 0; off >>= 1) {
        ps += __shfl_down(ps, off);
        pd += __shfl_down(pd, off);
    }
    if (l == 0) { s[v] = ps; d[v] = pd; }
}

// ---------------------------------------------------------------------------
// GAT aggregation, one wave per destination node over CSR (h2 bf16)
// ---------------------------------------------------------------------------
__global__ __launch_bounds__(256) void agg_k(
    const unsigned short* __restrict__ h2, const float* __restrict__ s,
    const float* __restrict__ d, const int* __restrict__ rowptr,
    const unsigned short* __restrict__ col, const void* __restrict__ bias,
    const int* __restrict__ dflag, unsigned short* __restrict__ out, int M)
{
    int f32 = dflag[0];
    int v = (blockIdx.x * blockDim.x + threadIdx.x) >> 6;
    int l = threadIdx.x & 63;
    if (v >= M) return;
    int st = rowptr[v], en = rowptr[v + 1];
    int deg = en - st;
    int  c0 = l, c1 = 64 + l;
    bool has2 = (l < 32);
    if (deg <= 0) {   // defensive; self-loops guarantee deg >= 1
        out[(size_t)v * 96 + c0] = f2bf(ldf(bias, c0, f32));
        if (has2) out[(size_t)v * 96 + c1] = f2bf(ldf(bias, c1, f32));
        return;
    }
    float dv = d[v];

    // pass 1: max score
    float lm = -1e30f;
    for (int i = l; i < deg; i += 64) {
        float e = s[col[st + i]] + dv;
        e = e >= 0.f ? e : 0.2f * e;
        lm = fmaxf(lm, e);
    }
    #pragma unroll
    for (int off = 32; off > 0; off >>= 1) lm = fmaxf(lm, __shfl_xor(lm, off));

    // pass 2: sum exp
    float ls = 0.f;
    for (int i = l; i < deg; i += 64) {
        float e = s[col[st + i]] + dv;
        e = e >= 0.f ? e : 0.2f * e;
        ls += expf(e - lm);
    }
    #pragma unroll
    for (int off = 32; off > 0; off >>= 1) ls += __shfl_xor(ls, off);
    float rden = 1.0f / ls;

    // pass 3: weighted feature gather
    float acc0 = 0.f, acc1 = 0.f;
    for (int base = 0; base < deg; base += 64) {
        int i = base + l;
        int u = 0; float w = 0.f;
        if (i < deg) {
            u = col[st + i];
            float e = s[u] + dv;
            e = e >= 0.f ? e : 0.2f * e;
            w = expf(e - lm);
        }
        int cl = min(64, deg - base);
        for (int j = 0; j < cl; j++) {
            int   uj = __shfl(u, j);
            float wj = __shfl(w, j);
            const unsigned short* hr = h2 + (size_t)uj * 96;
            acc0 = fmaf(wj, bf2f(hr[c0]), acc0);
            if (has2) acc1 = fmaf(wj, bf2f(hr[c1]), acc1);
        }
    }
    out[(size_t)v * 96 + c0] = f2bf(acc0 * rden + ldf(bias, c0, f32));
    if (has2) out[(size_t)v * 96 + c1] = f2bf(acc1 * rden + ldf(bias, c1, f32));
}

// ---------------------------------------------------------------------------
// BatchNorm statistics / coefficients / apply(+residual+lrelu)
// ---------------------------------------------------------------------------
__global__ __launch_bounds__(192) void bnstats_k(const unsigned short* __restrict__ x,
                                                 float* __restrict__ sums, int M)
{
    int c  = threadIdx.x % 96;
    int g2 = threadIdx.x / 96;
    float s = 0.f, q = 0.f;
    for (int r = blockIdx.x * 2 + g2; r < M; r += gridDim.x * 2) {
        float v = bf2f(x[(size_t)r * 96 + c]);
        s += v; q += v * v;
    }
    __shared__ float lsd[192], lqd[192];
    lsd[threadIdx.x] = s; lqd[threadIdx.x] = q;
    __syncthreads();
    if (g2 == 0) {
        atomicAdd(&sums[c],      s + lsd[threadIdx.x + 96]);
        atomicAdd(&sums[96 + c], q + lqd[threadIdx.x + 96]);
    }
}

__global__ void bncoef_k(const float* __restrict__ sums,
                         const void* __restrict__ g_,
                         const void* __restrict__ b_,
                         const int* __restrict__ dflag,
                         float* __restrict__ coef)
{
    int c = threadIdx.x;
    if (c >= 96) return;
    int f32 = dflag[0];
    float mu  = sums[c] * (1.f / N_NODES);
    float var = sums[96 + c] * (1.f / N_NODES) - mu * mu;
    float rinv = 1.0f / sqrtf(var + BN_EPS);
    float sc = ldf(g_, c, f32) * rinv;
    coef[c]      = sc;
    coef[96 + c] = ldf(b_, c, f32) - mu * sc;
}

// x/out may alias (in-place): no __restrict__ on those.
__global__ __launch_bounds__(256) void bnapply_k(const unsigned short* x,
                                                 const float* __restrict__ coef,
                                                 const unsigned short* __restrict__ iden,
                                                 unsigned short* out, int n4)
{
    int i = blockIdx.x * blockDim.x + threadIdx.x;
    if (i >= n4) return;
    int c4 = (i % 24) * 4;
    uint2 xu = ((const uint2*)x)[i];
    uint2 iu = ((const uint2*)iden)[i];
    float4 sc = *(const float4*)&coef[c4];
    float4 sh = *(const float4*)&coef[96 + c4];
    float r0 = lrelu01(bf2f(xu.x & 0xffff) * sc.x + sh.x) + bf2f(iu.x & 0xffff);
    float r1 = lrelu01(bf2f(xu.x >> 16)    * sc.y + sh.y) + bf2f(iu.x >> 16);
    float r2 = lrelu01(bf2f(xu.y & 0xffff) * sc.z + sh.z) + bf2f(iu.y & 0xffff);
    float r3 = lrelu01(bf2f(xu.y >> 16)    * sc.w + sh.w) + bf2f(iu.y >> 16);
    uint2 ou;
    ou.x = (unsigned int)f2bf(r0) | ((unsigned int)f2bf(r1) << 16);
    ou.y = (unsigned int)f2bf(r2) | ((unsigned int)f2bf(r3) << 16);
    ((uint2*)out)[i] = ou;
}

// ---------------------------------------------------------------------------
// Poincare expmap0 factor per node (wave/node)
// ---------------------------------------------------------------------------
__global__ __launch_bounds__(256) void pfac_k(const unsigned short* __restrict__ h,
                                              float* __restrict__ f, int M)
{
    int v = (blockIdx.x * blockDim.x + threadIdx.x) >> 6;
    int l = threadIdx.x & 63;
    if (v >= M) return;
    const unsigned short* r = h + (size_t)v * 96;
    float x1 = bf2f(r[l]);
    float x2 = (l < 32) ? bf2f(r[64 + l]) : 0.f;
    float q = x1 * x1 + x2 * x2;
    #pragma unroll
    for (int off = 32; off > 0; off >>= 1) q += __shfl_down(q, off);
    if (l == 0) {
        float n = fmaxf(sqrtf(q), 1e-15f);
        f[v] = tanhf(n) / n;
    }
}

// ---------------------------------------------------------------------------
// Graph mean-pool with LDS staging (batch is sorted)
// ---------------------------------------------------------------------------
__global__ __launch_bounds__(192) void pool_k(const unsigned short* __restrict__ h,
                                              const float* __restrict__ f,
                                              const int* __restrict__ batch,
                                              float* __restrict__ pooled,
                                              float* __restrict__ gcnt, int M)
{
    __shared__ float lp[NG * 96];
    __shared__ float lc[NG];
    for (int i = threadIdx.x; i < NG * 96; i += 192) lp[i] = 0.f;
    for (int i = threadIdx.x; i < NG; i += 192) lc[i] = 0.f;
    __syncthreads();

    int c  = threadIdx.x % 96;
    int g2 = threadIdx.x / 96;
    int base = blockIdx.x * 512;
    int rend = min(base + 512, M);
    for (int r = base + g2; r < rend; r += 2) {
        int g = batch[r];
        atomicAdd(&lp[g * 96 + c], bf2f(h[(size_t)r * 96 + c]) * f[r]);
        if (c == 0) atomicAdd(&lc[g], 1.0f);
    }
    __syncthreads();
    for (int i = threadIdx.x; i < NG * 96; i += 192)
        if (lp[i] != 0.f) atomicAdd(&pooled[i], lp[i]);
    for (int i = threadIdx.x; i < NG; i += 192)
        if (lc[i] != 0.f) atomicAdd(&gcnt[i], lc[i]);
}

// ---------------------------------------------------------------------------
// Head: pooled/cnt -> fc3+lrelu -> fc4 -> out (dtype per flag)
// ---------------------------------------------------------------------------
__global__ void head_k(const float* __restrict__ pooled,
                       const float* __restrict__ gcnt,
                       const void* __restrict__ w3, const void* __restrict__ b3,
                       const void* __restrict__ w4, const void* __restrict__ b4,
                       const int* __restrict__ dflag, void* __restrict__ outv)
{
    int g = threadIdx.x;
    if (g >= NG) return;
    int f32 = dflag[0];
    float inv = 1.0f / fmaxf(gcnt[g], 1.0f);
    float p[96];
    #pragma unroll
    for (int c = 0; c < 96; c++) p[c] = pooled[g * 96 + c] * inv;
    float o[48];
    for (int j = 0; j < 48; j++) {
        float a = ldf(b3, j, f32);
        #pragma unroll
        for (int c = 0; c < 96; c++) a = fmaf(p[c], ldf(w3, c * 48 + j, f32), a);
        o[j] = lrelu01(a);
    }
    for (int q = 0; q < 4; q++) {
        float a = ldf(b4, q, f32);
        #pragma unroll
        for (int j = 0; j < 48; j++) a = fmaf(o[j], ldf(w4, j * 4 + q, f32), a);
        if (f32) ((float*)outv)[g * 4 + q] = a;
        else     ((unsigned short*)outv)[g * 4 + q] = f2bf(a);
    }
}

// ---------------------------------------------------------------------------
// CSR construction (col stored as uint16 — node ids < 65536)
// ---------------------------------------------------------------------------
__global__ __launch_bounds__(256) void count_k(const int* __restrict__ ei,
                                               int* __restrict__ cnt)
{
    int e = blockIdx.x * 256 + threadIdx.x;
    if (e >= ET) return;
    int dstv = (e < N_EDGES) ? ei[N_EDGES + e] : (e - N_EDGES);
    atomicAdd(&cnt[dstv], 1);
}

__global__ __launch_bounds__(1024) void scan1_k(const int* __restrict__ cnt,
                                                int* __restrict__ rp,
                                                int* __restrict__ bsum, int n)
{
    __shared__ int sd[1024];
    int i = blockIdx.x * 1024 + threadIdx.x;
    int v = (i < n) ? cnt[i] : 0;
    sd[threadIdx.x] = v;
    __syncthreads();
    for (int off = 1; off < 1024; off <<= 1) {
        int t = 0;
        if (threadIdx.x >= off) t = sd[threadIdx.x - off];
        __syncthreads();
        if (threadIdx.x >= off) sd[threadIdx.x] += t;
        __syncthreads();
    }
    if (i < n) rp[i + 1] = sd[threadIdx.x];
    if (threadIdx.x == 1023) bsum[blockIdx.x] = sd[1023];
}

__global__ void scan2_k(int* __restrict__ bsum, int nb)
{
    if (blockIdx.x == 0 && threadIdx.x == 0) {
        int s = 0;
        for (int i = 0; i < nb; i++) { int t = bsum[i]; bsum[i] = s; s += t; }
    }
}

__global__ __launch_bounds__(1024) void scan3_k(int* __restrict__ rp,
                                                const int* __restrict__ bsum, int n)
{
    int i = blockIdx.x * 1024 + threadIdx.x;
    if (i < n) rp[i + 1] += bsum[blockIdx.x];
    if (i == 0) rp[0] = 0;
}

__global__ __launch_bounds__(256) void scatter_k(const int* __restrict__ ei,
                                                 const int* __restrict__ rp,
                                                 int* __restrict__ fill,
                                                 unsigned short* __restrict__ col)
{
    int e = blockIdx.x * 256 + threadIdx.x;
    if (e >= ET) return;
    int srcv, dstv;
    if (e < N_EDGES) { srcv = ei[e]; dstv = ei[N_EDGES + e]; }
    else             { srcv = dstv = e - N_EDGES; }
    int p = rp[dstv] + atomicAdd(&fill[dstv], 1);
    col[p] = (unsigned short)srcv;
}

// ---------------------------------------------------------------------------
extern "C" void kernel_launch(void* const* d_in, const int* in_sizes, int n_in,
                              void* d_out, int out_size, void* d_ws, size_t ws_size,
                              hipStream_t stream)
{
    const void* x     = d_in[0];
    const int*  ei    = (const int*)d_in[1];
    const int*  batch = (const int*)d_in[2];
    const void* embW  = d_in[3];
    const void* embB  = d_in[4];
    const void* convW[3]  = { d_in[5],  d_in[9],  d_in[13] };
    const void* convAs[3] = { d_in[6],  d_in[10], d_in[14] };
    const void* convAd[3] = { d_in[7],  d_in[11], d_in[15] };
    const void* convB[3]  = { d_in[8],  d_in[12], d_in[16] };
    const void* fcW[2]    = { d_in[17], d_in[19] };
    const void* fcB[2]    = { d_in[18], d_in[20] };
    const void* bnG[3]    = { d_in[21], d_in[23], d_in[25] };
    const void* bnB[3]    = { d_in[22], d_in[24], d_in[26] };
    const void* fc3W = d_in[27];
    const void* fc3b = d_in[28];
    const void* fc4W = d_in[29];
    const void* fc4b = d_in[30];

    // ---- workspace layout (total ≈ 31.5 MiB) ----
    char* wp_ = (char*)d_ws;
    auto alloc = [&](size_t b) { char* p = wp_; wp_ += (b + 255) & ~(size_t)255; return p; };
    int*   dflag = (int*)alloc(256);
    unsigned short* ident = (unsigned short*)alloc((size_t)N_NODES * H * 2);
    unsigned short* hA    = (unsigned short*)alloc((size_t)N_NODES * H * 2);
    unsigned short* hB    = (unsigned short*)alloc((size_t)N_NODES * H * 2);
    float* s_sc  = (float*)alloc((size_t)N_NODES * 4);
    float* d_sc  = (float*)alloc((size_t)N_NODES * 4);
    float* fvec  = (float*)alloc((size_t)N_NODES * 4);
    float* bnsum = (float*)alloc(192 * 4);
    float* coef  = (float*)alloc(192 * 4);
    float* pooled= (float*)alloc((NG * H + NG) * 4);
    float* gcnt  = pooled + NG * H;
    int*   rowptr= (int*)alloc((size_t)(N_NODES + 1) * 4);
    int*   cnt   = (int*)alloc((size_t)N_NODES * 4);
    unsigned short* col = (unsigned short*)alloc((size_t)ET * 2);
    int*   bsum  = (int*)alloc(64 * 4);

    const int NB = (N_NODES + 1023) / 1024;      // 49 scan blocks
    const int GE = (ET + 255) / 256;             // edge-parallel grid
    const int GM = (N_NODES + 63) / 64;          // gemm grid
    const int GW = (N_NODES * 64 + 255) / 256;   // wave-per-node grid
    const int N4 = N_NODES * H / 4;

    // ---- dtype detect ----
    detect_k<<<1, 64, 0, stream>>>((const unsigned short*)x, dflag);

    // ---- CSR build ----
    hipMemsetAsync(cnt, 0, (size_t)N_NODES * 4, stream);
    count_k<<<GE, 256, 0, stream>>>(ei, cnt);
    scan1_k<<<NB, 1024, 0, stream>>>(cnt, rowptr, bsum, N_NODES);
    scan2_k<<<1, 64, 0, stream>>>(bsum, NB);
    scan3_k<<<NB, 1024, 0, stream>>>(rowptr, bsum, N_NODES);
    hipMemsetAsync(cnt, 0, (size_t)N_NODES * 4, stream);
    scatter_k<<<GE, 256, 0, stream>>>(ei, rowptr, cnt, col);

    // ---- embed: h = lrelu(x @ embW + embB), identity = h ----
    gemm_k<2, 0><<<GM, 256, 0, stream>>>(x, embW, embB, dflag, hA, ident, N_NODES, F_IN);

    unsigned short* hcur = hA;
    unsigned short* htmp = hB;

    for (int l = 0; l < 3; l++) {
        // h2 = h @ convW
        gemm_k<0, 1><<<GM, 256, 0, stream>>>(hcur, convW[l], nullptr, dflag, htmp, nullptr, N_NODES, H);
        sd_k<<<GW, 256, 0, stream>>>(htmp, convAs[l], convAd[l], dflag, s_sc, d_sc, N_NODES);
        agg_k<<<GW, 256, 0, stream>>>(htmp, s_sc, d_sc, rowptr, col, convB[l], dflag, hcur, N_NODES);
        // BN + lrelu + residual
        hipMemsetAsync(bnsum, 0, 192 * 4, stream);
        bnstats_k<<<256, 192, 0, stream>>>(hcur, bnsum, N_NODES);
        bncoef_k<<<1, 128, 0, stream>>>(bnsum, bnG[l], bnB[l], dflag, coef);
        bnapply_k<<<(N4 + 255) / 256, 256, 0, stream>>>(hcur, coef, ident, hcur, N4);
        if (l < 2) {
            gemm_k<1, 1><<<GM, 256, 0, stream>>>(hcur, fcW[l], fcB[l], dflag, htmp, nullptr, N_NODES, H);
            unsigned short* t = hcur; hcur = htmp; htmp = t;
        }
    }

    // ---- Poincare + pooling + head ----
    pfac_k<<<GW, 256, 0, stream>>>(hcur, fvec, N_NODES);
    hipMemsetAsync(pooled, 0, (size_t)(NG * H + NG) * 4, stream);
    pool_k<<<(N_NODES + 511) / 512, 192, 0, stream>>>(hcur, fvec, batch, pooled, gcnt, N_NODES);
    head_k<<<1, 64, 0, stream>>>(pooled, gcnt, fc3W, fc3b, fc4W, fc4b, dflag, d_out);
}

// Round 4
// 880.161 us; speedup vs baseline: 1.4467x; 1.4467x over previous
//
#include <hip/hip_runtime.h>
#include <hip/hip_bf16.h>

#define DEVINL __device__ __forceinline__

constexpr int N_NODES = 50000;
constexpr int N_EDGES = 800000;
constexpr int ET      = N_EDGES + N_NODES;   // edges + self loops
constexpr int F_IN    = 256;
constexpr int H       = 96;
constexpr int NG      = 64;                  // graphs
constexpr float BN_EPS = 1e-5f;

DEVINL float bf2f(unsigned int u) {
    union { unsigned int i; float f; } c; c.i = u << 16; return c.f;
}
DEVINL unsigned short f2bf(float f) {
    union { float f; unsigned int i; } c; c.f = f;
    unsigned int x = c.i;
    return (unsigned short)((x + 0x7fffu + ((x >> 16) & 1u)) >> 16);
}
DEVINL float lrelu01(float v) { return v >= 0.f ? v : 0.01f * v; }
// dtype-flag aware scalar load of a "float tensor" input
DEVINL float ldf(const void* p, size_t i, int f32) {
    return f32 ? ((const float*)p)[i] : bf2f(((const unsigned short*)p)[i]);
}

// ---------------------------------------------------------------------------
// dtype detection: interpret first 64 shorts of x as bf16. fp32-backed data
// has random mantissa shorts -> many |v|>1e4/NaN. bf16-backed -> none.
// ---------------------------------------------------------------------------
__global__ void detect_k(const unsigned short* __restrict__ x, int* __restrict__ flag)
{
    int l = threadIdx.x;
    float f = bf2f(x[l]);
    bool huge = !(fabsf(f) <= 1e4f);          // catches NaN/Inf too
    unsigned long long m = __ballot(huge);
    if (l == 0) flag[0] = (__popcll(m) >= 8) ? 1 : 0;   // 1 = fp32, 0 = bf16
}

// ---------------------------------------------------------------------------
// GEMM: out[M,96] = A[M,K] @ W[K,96]  (A,W per dflag; out bf16; fp32 accum)
// EPI: 0 = plain, 1 = lrelu(acc+bias), 2 = lrelu(acc+bias) -> out and out2
// AWS: 1 if A lives in workspace (always bf16), 0 if A is an input (per dflag)
// ---------------------------------------------------------------------------
template<int EPI, int AWS>
__global__ __launch_bounds__(256) void gemm_k(
    const void* __restrict__ Ap, const void* __restrict__ Wp,
    const void* __restrict__ bp, const int* __restrict__ dflag,
    unsigned short* __restrict__ out, unsigned short* __restrict__ out2,
    int M, int K)
{
    __shared__ float As[64][36];
    __shared__ float Ws[32][96];
    const int f32  = AWS ? 0 : dflag[0];
    const int wf32 = dflag[0];
    const int tid  = threadIdx.x;
    const int row0 = blockIdx.x * 64;
    const int tm0  = (tid >> 4) << 2;   // 0..60
    const int tn0  = (tid & 15) * 6;    // 0..90
    const int lm   = tid >> 2;          // load row 0..63
    const int lk   = (tid & 3) << 3;    // 0,8,16,24
    const int lr   = row0 + lm;

    float acc[4][6] = {};

    for (int kc = 0; kc < K; kc += 32) {
        if (lr < M) {
            if (f32) {
                const float* A = (const float*)Ap;
                const float4* p = (const float4*)(A + (size_t)lr * K + kc + lk);
                float4 v0 = p[0], v1 = p[1];
                *(float4*)&As[lm][lk]     = v0;
                *(float4*)&As[lm][lk + 4] = v1;
            } else {
                const unsigned short* A = (const unsigned short*)Ap;
                uint4 u = *(const uint4*)(A + (size_t)lr * K + kc + lk);
                *(float4*)&As[lm][lk]     = make_float4(bf2f(u.x & 0xffff), bf2f(u.x >> 16),
                                                        bf2f(u.y & 0xffff), bf2f(u.y >> 16));
                *(float4*)&As[lm][lk + 4] = make_float4(bf2f(u.z & 0xffff), bf2f(u.z >> 16),
                                                        bf2f(u.w & 0xffff), bf2f(u.w >> 16));
            }
        } else {
            *(float4*)&As[lm][lk]     = make_float4(0.f, 0.f, 0.f, 0.f);
            *(float4*)&As[lm][lk + 4] = make_float4(0.f, 0.f, 0.f, 0.f);
        }

        #pragma unroll
        for (int p = 0; p < 3; p++) {
            int f = p * 1024 + tid * 4;
            int k = f / 96, j = f - k * 96;   // j is a multiple of 4
            if (wf32) {
                const float* W = (const float*)Wp;
                *(float4*)&Ws[k][j] = *(const float4*)(W + (size_t)(kc + k) * 96 + j);
            } else {
                const unsigned short* W = (const unsigned short*)Wp;
                uint2 u = *(const uint2*)(W + (size_t)(kc + k) * 96 + j);
                *(float4*)&Ws[k][j] = make_float4(bf2f(u.x & 0xffff), bf2f(u.x >> 16),
                                                  bf2f(u.y & 0xffff), bf2f(u.y >> 16));
            }
        }
        __syncthreads();

        #pragma unroll
        for (int kk = 0; kk < 32; kk++) {
            float aa[4];
            aa[0] = As[tm0 + 0][kk]; aa[1] = As[tm0 + 1][kk];
            aa[2] = As[tm0 + 2][kk]; aa[3] = As[tm0 + 3][kk];
            const float2* wp2 = (const float2*)&Ws[kk][tn0];
            float2 w01 = wp2[0], w23 = wp2[1], w45 = wp2[2];
            float wv[6] = { w01.x, w01.y, w23.x, w23.y, w45.x, w45.y };
            #pragma unroll
            for (int i = 0; i < 4; i++)
                #pragma unroll
                for (int j = 0; j < 6; j++)
                    acc[i][j] = fmaf(aa[i], wv[j], acc[i][j]);
        }
        __syncthreads();
    }

    float bv[6];
    if (EPI > 0) {
        #pragma unroll
        for (int j = 0; j < 6; j++) bv[j] = ldf(bp, tn0 + j, wf32);
    }
    #pragma unroll
    for (int i = 0; i < 4; i++) {
        int r = row0 + tm0 + i;
        if (r >= M) continue;
        size_t o = (size_t)r * 96 + tn0;   // even -> 4B-aligned bf16 addr
        unsigned int pk[3];
        #pragma unroll
        for (int j = 0; j < 3; j++) {
            float v0 = acc[i][2 * j], v1 = acc[i][2 * j + 1];
            if (EPI > 0) {
                v0 = lrelu01(v0 + bv[2 * j]);
                v1 = lrelu01(v1 + bv[2 * j + 1]);
            }
            pk[j] = (unsigned int)f2bf(v0) | ((unsigned int)f2bf(v1) << 16);
        }
        unsigned int* po = (unsigned int*)(out + o);
        po[0] = pk[0]; po[1] = pk[1]; po[2] = pk[2];
        if (EPI == 2) {
            unsigned int* po2 = (unsigned int*)(out2 + o);
            po2[0] = pk[0]; po2[1] = pk[1]; po2[2] = pk[2];
        }
    }
}

// ---------------------------------------------------------------------------
// Per-node attention scalars: s[v] = h2[v]·a_s, d[v] = h2[v]·a_d (wave/node)
// ---------------------------------------------------------------------------
__global__ __launch_bounds__(256) void sd_k(
    const unsigned short* __restrict__ h2, const void* __restrict__ as_,
    const void* __restrict__ ad_, const int* __restrict__ dflag,
    float* __restrict__ s, float* __restrict__ d, int M)
{
    int f32 = dflag[0];
    int v = (blockIdx.x * blockDim.x + threadIdx.x) >> 6;
    int l = threadIdx.x & 63;
    if (v >= M) return;
    const unsigned short* r = h2 + (size_t)v * 96;
    float x1 = bf2f(r[l]);
    float x2 = (l < 32) ? bf2f(r[64 + l]) : 0.f;
    float as1 = ldf(as_, l, f32),  ad1 = ldf(ad_, l, f32);
    float as2 = (l < 32) ? ldf(as_, 64 + l, f32) : 0.f;
    float ad2 = (l < 32) ? ldf(ad_, 64 + l, f32) : 0.f;
    float ps = x1 * as1 + x2 * as2;
    float pd = x1 * ad1 + x2 * ad2;
    #pragma unroll
    for (int off = 32; off > 0; off >>= 1) {
        ps += __shfl_down(ps, off);
        pd += __shfl_down(pd, off);
    }
    if (l == 0) { s[v] = ps; d[v] = pd; }
}

// ---------------------------------------------------------------------------
// GAT aggregation, one wave per destination node over CSR (h2 bf16)
// ---------------------------------------------------------------------------
__global__ __launch_bounds__(256) void agg_k(
    const unsigned short* __restrict__ h2, const float* __restrict__ s,
    const float* __restrict__ d, const int* __restrict__ rowptr,
    const unsigned short* __restrict__ col, const void* __restrict__ bias,
    const int* __restrict__ dflag, unsigned short* __restrict__ out, int M)
{
    int f32 = dflag[0];
    int v = (blockIdx.x * blockDim.x + threadIdx.x) >> 6;
    int l = threadIdx.x & 63;
    if (v >= M) return;
    int st = rowptr[v], en = rowptr[v + 1];
    int deg = en - st;
    int  c0 = l, c1 = 64 + l;
    bool has2 = (l < 32);
    if (deg <= 0) {   // defensive; self-loops guarantee deg >= 1
        out[(size_t)v * 96 + c0] = f2bf(ldf(bias, c0, f32));
        if (has2) out[(size_t)v * 96 + c1] = f2bf(ldf(bias, c1, f32));
        return;
    }
    float dv = d[v];

    // pass 1: max score
    float lm = -1e30f;
    for (int i = l; i < deg; i += 64) {
        float e = s[col[st + i]] + dv;
        e = e >= 0.f ? e : 0.2f * e;
        lm = fmaxf(lm, e);
    }
    #pragma unroll
    for (int off = 32; off > 0; off >>= 1) lm = fmaxf(lm, __shfl_xor(lm, off));

    // pass 2: sum exp
    float ls = 0.f;
    for (int i = l; i < deg; i += 64) {
        float e = s[col[st + i]] + dv;
        e = e >= 0.f ? e : 0.2f * e;
        ls += expf(e - lm);
    }
    #pragma unroll
    for (int off = 32; off > 0; off >>= 1) ls += __shfl_xor(ls, off);
    float rden = 1.0f / ls;

    // pass 3: weighted feature gather
    float acc0 = 0.f, acc1 = 0.f;
    for (int base = 0; base < deg; base += 64) {
        int i = base + l;
        int u = 0; float w = 0.f;
        if (i < deg) {
            u = col[st + i];
            float e = s[u] + dv;
            e = e >= 0.f ? e : 0.2f * e;
            w = expf(e - lm);
        }
        int cl = min(64, deg - base);
        for (int j = 0; j < cl; j++) {
            int   uj = __shfl(u, j);
            float wj = __shfl(w, j);
            const unsigned short* hr = h2 + (size_t)uj * 96;
            acc0 = fmaf(wj, bf2f(hr[c0]), acc0);
            if (has2) acc1 = fmaf(wj, bf2f(hr[c1]), acc1);
        }
    }
    out[(size_t)v * 96 + c0] = f2bf(acc0 * rden + ldf(bias, c0, f32));
    if (has2) out[(size_t)v * 96 + c1] = f2bf(acc1 * rden + ldf(bias, c1, f32));
}

// ---------------------------------------------------------------------------
// BatchNorm statistics / coefficients / apply(+residual+lrelu)
// ---------------------------------------------------------------------------
__global__ __launch_bounds__(192) void bnstats_k(const unsigned short* __restrict__ x,
                                                 float* __restrict__ sums, int M)
{
    int c  = threadIdx.x % 96;
    int g2 = threadIdx.x / 96;
    float s = 0.f, q = 0.f;
    for (int r = blockIdx.x * 2 + g2; r < M; r += gridDim.x * 2) {
        float v = bf2f(x[(size_t)r * 96 + c]);
        s += v; q += v * v;
    }
    __shared__ float lsd[192], lqd[192];
    lsd[threadIdx.x] = s; lqd[threadIdx.x] = q;
    __syncthreads();
    if (g2 == 0) {
        atomicAdd(&sums[c],      s + lsd[threadIdx.x + 96]);
        atomicAdd(&sums[96 + c], q + lqd[threadIdx.x + 96]);
    }
}

__global__ void bncoef_k(const float* __restrict__ sums,
                         const void* __restrict__ g_,
                         const void* __restrict__ b_,
                         const int* __restrict__ dflag,
                         float* __restrict__ coef)
{
    int c = threadIdx.x;
    if (c >= 96) return;
    int f32 = dflag[0];
    float mu  = sums[c] * (1.f / N_NODES);
    float var = sums[96 + c] * (1.f / N_NODES) - mu * mu;
    float rinv = 1.0f / sqrtf(var + BN_EPS);
    float sc = ldf(g_, c, f32) * rinv;
    coef[c]      = sc;
    coef[96 + c] = ldf(b_, c, f32) - mu * sc;
}

// x/out may alias (in-place): no __restrict__ on those.
__global__ __launch_bounds__(256) void bnapply_k(const unsigned short* x,
                                                 const float* __restrict__ coef,
                                                 const unsigned short* __restrict__ iden,
                                                 unsigned short* out, int n4)
{
    int i = blockIdx.x * blockDim.x + threadIdx.x;
    if (i >= n4) return;
    int c4 = (i % 24) * 4;
    uint2 xu = ((const uint2*)x)[i];
    uint2 iu = ((const uint2*)iden)[i];
    float4 sc = *(const float4*)&coef[c4];
    float4 sh = *(const float4*)&coef[96 + c4];
    float r0 = lrelu01(bf2f(xu.x & 0xffff) * sc.x + sh.x) + bf2f(iu.x & 0xffff);
    float r1 = lrelu01(bf2f(xu.x >> 16)    * sc.y + sh.y) + bf2f(iu.x >> 16);
    float r2 = lrelu01(bf2f(xu.y & 0xffff) * sc.z + sh.z) + bf2f(iu.y & 0xffff);
    float r3 = lrelu01(bf2f(xu.y >> 16)    * sc.w + sh.w) + bf2f(iu.y >> 16);
    uint2 ou;
    ou.x = (unsigned int)f2bf(r0) | ((unsigned int)f2bf(r1) << 16);
    ou.y = (unsigned int)f2bf(r2) | ((unsigned int)f2bf(r3) << 16);
    ((uint2*)out)[i] = ou;
}

// ---------------------------------------------------------------------------
// Poincare expmap0 factor per node (wave/node)
// ---------------------------------------------------------------------------
__global__ __launch_bounds__(256) void pfac_k(const unsigned short* __restrict__ h,
                                              float* __restrict__ f, int M)
{
    int v = (blockIdx.x * blockDim.x + threadIdx.x) >> 6;
    int l = threadIdx.x & 63;
    if (v >= M) return;
    const unsigned short* r = h + (size_t)v * 96;
    float x1 = bf2f(r[l]);
    float x2 = (l < 32) ? bf2f(r[64 + l]) : 0.f;
    float q = x1 * x1 + x2 * x2;
    #pragma unroll
    for (int off = 32; off > 0; off >>= 1) q += __shfl_down(q, off);
    if (l == 0) {
        float n = fmaxf(sqrtf(q), 1e-15f);
        f[v] = tanhf(n) / n;
    }
}

// ---------------------------------------------------------------------------
// Graph mean-pool with LDS staging (batch is sorted)
// ---------------------------------------------------------------------------
__global__ __launch_bounds__(192) void pool_k(const unsigned short* __restrict__ h,
                                              const float* __restrict__ f,
                                              const int* __restrict__ batch,
                                              float* __restrict__ pooled,
                                              float* __restrict__ gcnt, int M)
{
    __shared__ float lp[NG * 96];
    __shared__ float lc[NG];
    for (int i = threadIdx.x; i < NG * 96; i += 192) lp[i] = 0.f;
    for (int i = threadIdx.x; i < NG; i += 192) lc[i] = 0.f;
    __syncthreads();

    int c  = threadIdx.x % 96;
    int g2 = threadIdx.x / 96;
    int base = blockIdx.x * 512;
    int rend = min(base + 512, M);
    for (int r = base + g2; r < rend; r += 2) {
        int g = batch[r];
        atomicAdd(&lp[g * 96 + c], bf2f(h[(size_t)r * 96 + c]) * f[r]);
        if (c == 0) atomicAdd(&lc[g], 1.0f);
    }
    __syncthreads();
    for (int i = threadIdx.x; i < NG * 96; i += 192)
        if (lp[i] != 0.f) atomicAdd(&pooled[i], lp[i]);
    for (int i = threadIdx.x; i < NG; i += 192)
        if (lc[i] != 0.f) atomicAdd(&gcnt[i], lc[i]);
}

// ---------------------------------------------------------------------------
// Head: one block per graph. pooled/cnt -> fc3+lrelu -> fc4 -> out.
// Replaces the single-wave serial head (430 us latency-bound: 4608 dependent
// scalar loads/thread, 1 wave on 1 CU). 64 blocks x 64 threads, LDS-staged.
// ---------------------------------------------------------------------------
__global__ __launch_bounds__(64) void head_k(const float* __restrict__ pooled,
                                             const float* __restrict__ gcnt,
                                             const void* __restrict__ w3,
                                             const void* __restrict__ b3,
                                             const void* __restrict__ w4,
                                             const void* __restrict__ b4,
                                             const int* __restrict__ dflag,
                                             void* __restrict__ outv)
{
    int g = blockIdx.x;
    int t = threadIdx.x;
    int f32 = dflag[0];
    __shared__ float p[96];
    __shared__ float o[48];
    float inv = 1.0f / fmaxf(gcnt[g], 1.0f);
    for (int c = t; c < 96; c += 64) p[c] = pooled[g * 96 + c] * inv;
    __syncthreads();
    if (t < 48) {
        float a = ldf(b3, t, f32);
        #pragma unroll
        for (int c = 0; c < 96; c++) a = fmaf(p[c], ldf(w3, (size_t)c * 48 + t, f32), a);
        o[t] = lrelu01(a);
    }
    __syncthreads();
    if (t < 4) {
        float a = ldf(b4, t, f32);
        #pragma unroll
        for (int j = 0; j < 48; j++) a = fmaf(o[j], ldf(w4, j * 4 + t, f32), a);
        if (f32) ((float*)outv)[g * 4 + t] = a;
        else     ((unsigned short*)outv)[g * 4 + t] = f2bf(a);
    }
}

// ---------------------------------------------------------------------------
// CSR construction (col stored as uint16 — node ids < 65536)
// ---------------------------------------------------------------------------
__global__ __launch_bounds__(256) void count_k(const int* __restrict__ ei,
                                               int* __restrict__ cnt)
{
    int e = blockIdx.x * 256 + threadIdx.x;
    if (e >= ET) return;
    int dstv = (e < N_EDGES) ? ei[N_EDGES + e] : (e - N_EDGES);
    atomicAdd(&cnt[dstv], 1);
}

__global__ __launch_bounds__(1024) void scan1_k(const int* __restrict__ cnt,
                                                int* __restrict__ rp,
                                                int* __restrict__ bsum, int n)
{
    __shared__ int sd[1024];
    int i = blockIdx.x * 1024 + threadIdx.x;
    int v = (i < n) ? cnt[i] : 0;
    sd[threadIdx.x] = v;
    __syncthreads();
    for (int off = 1; off < 1024; off <<= 1) {
        int t = 0;
        if (threadIdx.x >= off) t = sd[threadIdx.x - off];
        __syncthreads();
        if (threadIdx.x >= off) sd[threadIdx.x] += t;
        __syncthreads();
    }
    if (i < n) rp[i + 1] = sd[threadIdx.x];
    if (threadIdx.x == 1023) bsum[blockIdx.x] = sd[1023];
}

__global__ void scan2_k(int* __restrict__ bsum, int nb)
{
    if (blockIdx.x == 0 && threadIdx.x == 0) {
        int s = 0;
        for (int i = 0; i < nb; i++) { int t = bsum[i]; bsum[i] = s; s += t; }
    }
}

__global__ __launch_bounds__(1024) void scan3_k(int* __restrict__ rp,
                                                const int* __restrict__ bsum, int n)
{
    int i = blockIdx.x * 1024 + threadIdx.x;
    if (i < n) rp[i + 1] += bsum[blockIdx.x];
    if (i == 0) rp[0] = 0;
}

__global__ __launch_bounds__(256) void scatter_k(const int* __restrict__ ei,
                                                 const int* __restrict__ rp,
                                                 int* __restrict__ fill,
                                                 unsigned short* __restrict__ col)
{
    int e = blockIdx.x * 256 + threadIdx.x;
    if (e >= ET) return;
    int srcv, dstv;
    if (e < N_EDGES) { srcv = ei[e]; dstv = ei[N_EDGES + e]; }
    else             { srcv = dstv = e - N_EDGES; }
    int p = rp[dstv] + atomicAdd(&fill[dstv], 1);
    col[p] = (unsigned short)srcv;
}

// ---------------------------------------------------------------------------
extern "C" void kernel_launch(void* const* d_in, const int* in_sizes, int n_in,
                              void* d_out, int out_size, void* d_ws, size_t ws_size,
                              hipStream_t stream)
{
    const void* x     = d_in[0];
    const int*  ei    = (const int*)d_in[1];
    const int*  batch = (const int*)d_in[2];
    const void* embW  = d_in[3];
    const void* embB  = d_in[4];
    const void* convW[3]  = { d_in[5],  d_in[9],  d_in[13] };
    const void* convAs[3] = { d_in[6],  d_in[10], d_in[14] };
    const void* convAd[3] = { d_in[7],  d_in[11], d_in[15] };
    const void* convB[3]  = { d_in[8],  d_in[12], d_in[16] };
    const void* fcW[2]    = { d_in[17], d_in[19] };
    const void* fcB[2]    = { d_in[18], d_in[20] };
    const void* bnG[3]    = { d_in[21], d_in[23], d_in[25] };
    const void* bnB[3]    = { d_in[22], d_in[24], d_in[26] };
    const void* fc3W = d_in[27];
    const void* fc3b = d_in[28];
    const void* fc4W = d_in[29];
    const void* fc4b = d_in[30];

    // ---- workspace layout (total ≈ 31.5 MiB) ----
    char* wp_ = (char*)d_ws;
    auto alloc = [&](size_t b) { char* p = wp_; wp_ += (b + 255) & ~(size_t)255; return p; };
    int*   dflag = (int*)alloc(256);
    unsigned short* ident = (unsigned short*)alloc((size_t)N_NODES * H * 2);
    unsigned short* hA    = (unsigned short*)alloc((size_t)N_NODES * H * 2);
    unsigned short* hB    = (unsigned short*)alloc((size_t)N_NODES * H * 2);
    float* s_sc  = (float*)alloc((size_t)N_NODES * 4);
    float* d_sc  = (float*)alloc((size_t)N_NODES * 4);
    float* fvec  = (float*)alloc((size_t)N_NODES * 4);
    float* bnsum = (float*)alloc(192 * 4);
    float* coef  = (float*)alloc(192 * 4);
    float* pooled= (float*)alloc((NG * H + NG) * 4);
    float* gcnt  = pooled + NG * H;
    int*   rowptr= (int*)alloc((size_t)(N_NODES + 1) * 4);
    int*   cnt   = (int*)alloc((size_t)N_NODES * 4);
    unsigned short* col = (unsigned short*)alloc((size_t)ET * 2);
    int*   bsum  = (int*)alloc(64 * 4);

    const int NB = (N_NODES + 1023) / 1024;      // 49 scan blocks
    const int GE = (ET + 255) / 256;             // edge-parallel grid
    const int GM = (N_NODES + 63) / 64;          // gemm grid
    const int GW = (N_NODES * 64 + 255) / 256;   // wave-per-node grid
    const int N4 = N_NODES * H / 4;

    // ---- dtype detect ----
    detect_k<<<1, 64, 0, stream>>>((const unsigned short*)x, dflag);

    // ---- CSR build ----
    hipMemsetAsync(cnt, 0, (size_t)N_NODES * 4, stream);
    count_k<<<GE, 256, 0, stream>>>(ei, cnt);
    scan1_k<<<NB, 1024, 0, stream>>>(cnt, rowptr, bsum, N_NODES);
    scan2_k<<<1, 64, 0, stream>>>(bsum, NB);
    scan3_k<<<NB, 1024, 0, stream>>>(rowptr, bsum, N_NODES);
    hipMemsetAsync(cnt, 0, (size_t)N_NODES * 4, stream);
    scatter_k<<<GE, 256, 0, stream>>>(ei, rowptr, cnt, col);

    // ---- embed: h = lrelu(x @ embW + embB), identity = h ----
    gemm_k<2, 0><<<GM, 256, 0, stream>>>(x, embW, embB, dflag, hA, ident, N_NODES, F_IN);

    unsigned short* hcur = hA;
    unsigned short* htmp = hB;

    for (int l = 0; l < 3; l++) {
        // h2 = h @ convW
        gemm_k<0, 1><<<GM, 256, 0, stream>>>(hcur, convW[l], nullptr, dflag, htmp, nullptr, N_NODES, H);
        sd_k<<<GW, 256, 0, stream>>>(htmp, convAs[l], convAd[l], dflag, s_sc, d_sc, N_NODES);
        agg_k<<<GW, 256, 0, stream>>>(htmp, s_sc, d_sc, rowptr, col, convB[l], dflag, hcur, N_NODES);
        // BN + lrelu + residual
        hipMemsetAsync(bnsum, 0, 192 * 4, stream);
        bnstats_k<<<256, 192, 0, stream>>>(hcur, bnsum, N_NODES);
        bncoef_k<<<1, 128, 0, stream>>>(bnsum, bnG[l], bnB[l], dflag, coef);
        bnapply_k<<<(N4 + 255) / 256, 256, 0, stream>>>(hcur, coef, ident, hcur, N4);
        if (l < 2) {
            gemm_k<1, 1><<<GM, 256, 0, stream>>>(hcur, fcW[l], fcB[l], dflag, htmp, nullptr, N_NODES, H);
            unsigned short* t = hcur; hcur = htmp; htmp = t;
        }
    }

    // ---- Poincare + pooling + head ----
    pfac_k<<<GW, 256, 0, stream>>>(hcur, fvec, N_NODES);
    hipMemsetAsync(pooled, 0, (size_t)(NG * H + NG) * 4, stream);
    pool_k<<<(N_NODES + 511) / 512, 192, 0, stream>>>(hcur, fvec, batch, pooled, gcnt, N_NODES);
    head_k<<<NG, 64, 0, stream>>>(pooled, gcnt, fc3W, fc3b, fc4W, fc4b, dflag, d_out);
}

// Round 5
// 820.856 us; speedup vs baseline: 1.5512x; 1.0722x over previous
//
#include <hip/hip_runtime.h>
#include <hip/hip_bf16.h>

#define DEVINL __device__ __forceinline__

constexpr int N_NODES = 50000;
constexpr int N_EDGES = 800000;
constexpr int ET      = N_EDGES + N_NODES;   // edges + self loops
constexpr int F_IN    = 256;
constexpr int H       = 96;
constexpr int NG      = 64;                  // graphs
constexpr float BN_EPS = 1e-5f;

DEVINL float bf2f(unsigned int u) {
    union { unsigned int i; float f; } c; c.i = u << 16; return c.f;
}
DEVINL unsigned short f2bf(float f) {
    union { float f; unsigned int i; } c; c.f = f;
    unsigned int x = c.i;
    return (unsigned short)((x + 0x7fffu + ((x >> 16) & 1u)) >> 16);
}
DEVINL float lrelu01(float v) { return v >= 0.f ? v : 0.01f * v; }
// dtype-flag aware scalar load of a "float tensor" input
DEVINL float ldf(const void* p, size_t i, int f32) {
    return f32 ? ((const float*)p)[i] : bf2f(((const unsigned short*)p)[i]);
}

// ---------------------------------------------------------------------------
// dtype detection: interpret first 64 shorts of x as bf16. fp32-backed data
// has random mantissa shorts -> many |v|>1e4/NaN. bf16-backed -> none.
// ---------------------------------------------------------------------------
__global__ void detect_k(const unsigned short* __restrict__ x, int* __restrict__ flag)
{
    int l = threadIdx.x;
    float f = bf2f(x[l]);
    bool huge = !(fabsf(f) <= 1e4f);          // catches NaN/Inf too
    unsigned long long m = __ballot(huge);
    if (l == 0) flag[0] = (__popcll(m) >= 8) ? 1 : 0;   // 1 = fp32, 0 = bf16
}

// ---------------------------------------------------------------------------
// GEMM: out[M,96] = A[M,K] @ W[K,96]  (A,W per dflag; out bf16; fp32 accum)
// EPI: 0 = plain, 1 = lrelu(acc+bias), 2 = lrelu(acc+bias) -> out and out2
// AWS: 1 if A lives in workspace (always bf16), 0 if A is an input (per dflag)
// ---------------------------------------------------------------------------
template<int EPI, int AWS>
__global__ __launch_bounds__(256) void gemm_k(
    const void* __restrict__ Ap, const void* __restrict__ Wp,
    const void* __restrict__ bp, const int* __restrict__ dflag,
    unsigned short* __restrict__ out, unsigned short* __restrict__ out2,
    int M, int K)
{
    __shared__ float As[64][36];
    __shared__ float Ws[32][96];
    const int f32  = AWS ? 0 : dflag[0];
    const int wf32 = dflag[0];
    const int tid  = threadIdx.x;
    const int row0 = blockIdx.x * 64;
    const int tm0  = (tid >> 4) << 2;   // 0..60
    const int tn0  = (tid & 15) * 6;    // 0..90
    const int lm   = tid >> 2;          // load row 0..63
    const int lk   = (tid & 3) << 3;    // 0,8,16,24
    const int lr   = row0 + lm;

    float acc[4][6] = {};

    for (int kc = 0; kc < K; kc += 32) {
        if (lr < M) {
            if (f32) {
                const float* A = (const float*)Ap;
                const float4* p = (const float4*)(A + (size_t)lr * K + kc + lk);
                float4 v0 = p[0], v1 = p[1];
                *(float4*)&As[lm][lk]     = v0;
                *(float4*)&As[lm][lk + 4] = v1;
            } else {
                const unsigned short* A = (const unsigned short*)Ap;
                uint4 u = *(const uint4*)(A + (size_t)lr * K + kc + lk);
                *(float4*)&As[lm][lk]     = make_float4(bf2f(u.x & 0xffff), bf2f(u.x >> 16),
                                                        bf2f(u.y & 0xffff), bf2f(u.y >> 16));
                *(float4*)&As[lm][lk + 4] = make_float4(bf2f(u.z & 0xffff), bf2f(u.z >> 16),
                                                        bf2f(u.w & 0xffff), bf2f(u.w >> 16));
            }
        } else {
            *(float4*)&As[lm][lk]     = make_float4(0.f, 0.f, 0.f, 0.f);
            *(float4*)&As[lm][lk + 4] = make_float4(0.f, 0.f, 0.f, 0.f);
        }

        #pragma unroll
        for (int p = 0; p < 3; p++) {
            int f = p * 1024 + tid * 4;
            int k = f / 96, j = f - k * 96;   // j is a multiple of 4
            if (wf32) {
                const float* W = (const float*)Wp;
                *(float4*)&Ws[k][j] = *(const float4*)(W + (size_t)(kc + k) * 96 + j);
            } else {
                const unsigned short* W = (const unsigned short*)Wp;
                uint2 u = *(const uint2*)(W + (size_t)(kc + k) * 96 + j);
                *(float4*)&Ws[k][j] = make_float4(bf2f(u.x & 0xffff), bf2f(u.x >> 16),
                                                  bf2f(u.y & 0xffff), bf2f(u.y >> 16));
            }
        }
        __syncthreads();

        #pragma unroll
        for (int kk = 0; kk < 32; kk++) {
            float aa[4];
            aa[0] = As[tm0 + 0][kk]; aa[1] = As[tm0 + 1][kk];
            aa[2] = As[tm0 + 2][kk]; aa[3] = As[tm0 + 3][kk];
            const float2* wp2 = (const float2*)&Ws[kk][tn0];
            float2 w01 = wp2[0], w23 = wp2[1], w45 = wp2[2];
            float wv[6] = { w01.x, w01.y, w23.x, w23.y, w45.x, w45.y };
            #pragma unroll
            for (int i = 0; i < 4; i++)
                #pragma unroll
                for (int j = 0; j < 6; j++)
                    acc[i][j] = fmaf(aa[i], wv[j], acc[i][j]);
        }
        __syncthreads();
    }

    float bv[6];
    if (EPI > 0) {
        #pragma unroll
        for (int j = 0; j < 6; j++) bv[j] = ldf(bp, tn0 + j, wf32);
    }
    #pragma unroll
    for (int i = 0; i < 4; i++) {
        int r = row0 + tm0 + i;
        if (r >= M) continue;
        size_t o = (size_t)r * 96 + tn0;   // even -> 4B-aligned bf16 addr
        unsigned int pk[3];
        #pragma unroll
        for (int j = 0; j < 3; j++) {
            float v0 = acc[i][2 * j], v1 = acc[i][2 * j + 1];
            if (EPI > 0) {
                v0 = lrelu01(v0 + bv[2 * j]);
                v1 = lrelu01(v1 + bv[2 * j + 1]);
            }
            pk[j] = (unsigned int)f2bf(v0) | ((unsigned int)f2bf(v1) << 16);
        }
        unsigned int* po = (unsigned int*)(out + o);
        po[0] = pk[0]; po[1] = pk[1]; po[2] = pk[2];
        if (EPI == 2) {
            unsigned int* po2 = (unsigned int*)(out2 + o);
            po2[0] = pk[0]; po2[1] = pk[1]; po2[2] = pk[2];
        }
    }
}

// ---------------------------------------------------------------------------
// Per-node attention scalars: s[v] = h2[v]·a_s, d[v] = h2[v]·a_d (wave/node)
// ---------------------------------------------------------------------------
__global__ __launch_bounds__(256) void sd_k(
    const unsigned short* __restrict__ h2, const void* __restrict__ as_,
    const void* __restrict__ ad_, const int* __restrict__ dflag,
    float* __restrict__ s, float* __restrict__ d, int M)
{
    int f32 = dflag[0];
    int v = (blockIdx.x * blockDim.x + threadIdx.x) >> 6;
    int l = threadIdx.x & 63;
    if (v >= M) return;
    const unsigned short* r = h2 + (size_t)v * 96;
    float x1 = bf2f(r[l]);
    float x2 = (l < 32) ? bf2f(r[64 + l]) : 0.f;
    float as1 = ldf(as_, l, f32),  ad1 = ldf(ad_, l, f32);
    float as2 = (l < 32) ? ldf(as_, 64 + l, f32) : 0.f;
    float ad2 = (l < 32) ? ldf(ad_, 64 + l, f32) : 0.f;
    float ps = x1 * as1 + x2 * as2;
    float pd = x1 * ad1 + x2 * ad2;
    #pragma unroll
    for (int off = 32; off > 0; off >>= 1) {
        ps += __shfl_down(ps, off);
        pd += __shfl_down(pd, off);
    }
    if (l == 0) { s[v] = ps; d[v] = pd; }
}

// ---------------------------------------------------------------------------
// GAT aggregation, one wave per destination node over CSR (h2 bf16)
// ---------------------------------------------------------------------------
__global__ __launch_bounds__(256) void agg_k(
    const unsigned short* __restrict__ h2, const float* __restrict__ s,
    const float* __restrict__ d, const int* __restrict__ rowptr,
    const unsigned short* __restrict__ col, const void* __restrict__ bias,
    const int* __restrict__ dflag, unsigned short* __restrict__ out, int M)
{
    int f32 = dflag[0];
    int v = (blockIdx.x * blockDim.x + threadIdx.x) >> 6;
    int l = threadIdx.x & 63;
    if (v >= M) return;
    int st = rowptr[v], en = rowptr[v + 1];
    int deg = en - st;
    int  c0 = l, c1 = 64 + l;
    bool has2 = (l < 32);
    if (deg <= 0) {   // defensive; self-loops guarantee deg >= 1
        out[(size_t)v * 96 + c0] = f2bf(ldf(bias, c0, f32));
        if (has2) out[(size_t)v * 96 + c1] = f2bf(ldf(bias, c1, f32));
        return;
    }
    float dv = d[v];

    // pass 1: max score
    float lm = -1e30f;
    for (int i = l; i < deg; i += 64) {
        float e = s[col[st + i]] + dv;
        e = e >= 0.f ? e : 0.2f * e;
        lm = fmaxf(lm, e);
    }
    #pragma unroll
    for (int off = 32; off > 0; off >>= 1) lm = fmaxf(lm, __shfl_xor(lm, off));

    // pass 2: sum exp
    float ls = 0.f;
    for (int i = l; i < deg; i += 64) {
        float e = s[col[st + i]] + dv;
        e = e >= 0.f ? e : 0.2f * e;
        ls += expf(e - lm);
    }
    #pragma unroll
    for (int off = 32; off > 0; off >>= 1) ls += __shfl_xor(ls, off);
    float rden = 1.0f / ls;

    // pass 3: weighted feature gather
    float acc0 = 0.f, acc1 = 0.f;
    for (int base = 0; base < deg; base += 64) {
        int i = base + l;
        int u = 0; float w = 0.f;
        if (i < deg) {
            u = col[st + i];
            float e = s[u] + dv;
            e = e >= 0.f ? e : 0.2f * e;
            w = expf(e - lm);
        }
        int cl = min(64, deg - base);
        for (int j = 0; j < cl; j++) {
            int   uj = __shfl(u, j);
            float wj = __shfl(w, j);
            const unsigned short* hr = h2 + (size_t)uj * 96;
            acc0 = fmaf(wj, bf2f(hr[c0]), acc0);
            if (has2) acc1 = fmaf(wj, bf2f(hr[c1]), acc1);
        }
    }
    out[(size_t)v * 96 + c0] = f2bf(acc0 * rden + ldf(bias, c0, f32));
    if (has2) out[(size_t)v * 96 + c1] = f2bf(acc1 * rden + ldf(bias, c1, f32));
}

// ---------------------------------------------------------------------------
// BatchNorm statistics / coefficients / apply(+residual+lrelu)
// ---------------------------------------------------------------------------
__global__ __launch_bounds__(192) void bnstats_k(const unsigned short* __restrict__ x,
                                                 float* __restrict__ sums, int M)
{
    int c  = threadIdx.x % 96;
    int g2 = threadIdx.x / 96;
    float s = 0.f, q = 0.f;
    for (int r = blockIdx.x * 2 + g2; r < M; r += gridDim.x * 2) {
        float v = bf2f(x[(size_t)r * 96 + c]);
        s += v; q += v * v;
    }
    __shared__ float lsd[192], lqd[192];
    lsd[threadIdx.x] = s; lqd[threadIdx.x] = q;
    __syncthreads();
    if (g2 == 0) {
        atomicAdd(&sums[c],      s + lsd[threadIdx.x + 96]);
        atomicAdd(&sums[96 + c], q + lqd[threadIdx.x + 96]);
    }
}

__global__ void bncoef_k(const float* __restrict__ sums,
                         const void* __restrict__ g_,
                         const void* __restrict__ b_,
                         const int* __restrict__ dflag,
                         float* __restrict__ coef)
{
    int c = threadIdx.x;
    if (c >= 96) return;
    int f32 = dflag[0];
    float mu  = sums[c] * (1.f / N_NODES);
    float var = sums[96 + c] * (1.f / N_NODES) - mu * mu;
    float rinv = 1.0f / sqrtf(var + BN_EPS);
    float sc = ldf(g_, c, f32) * rinv;
    coef[c]      = sc;
    coef[96 + c] = ldf(b_, c, f32) - mu * sc;
}

// x/out may alias (in-place): no __restrict__ on those.
__global__ __launch_bounds__(256) void bnapply_k(const unsigned short* x,
                                                 const float* __restrict__ coef,
                                                 const unsigned short* __restrict__ iden,
                                                 unsigned short* out, int n4)
{
    int i = blockIdx.x * blockDim.x + threadIdx.x;
    if (i >= n4) return;
    int c4 = (i % 24) * 4;
    uint2 xu = ((const uint2*)x)[i];
    uint2 iu = ((const uint2*)iden)[i];
    float4 sc = *(const float4*)&coef[c4];
    float4 sh = *(const float4*)&coef[96 + c4];
    float r0 = lrelu01(bf2f(xu.x & 0xffff) * sc.x + sh.x) + bf2f(iu.x & 0xffff);
    float r1 = lrelu01(bf2f(xu.x >> 16)    * sc.y + sh.y) + bf2f(iu.x >> 16);
    float r2 = lrelu01(bf2f(xu.y & 0xffff) * sc.z + sh.z) + bf2f(iu.y & 0xffff);
    float r3 = lrelu01(bf2f(xu.y >> 16)    * sc.w + sh.w) + bf2f(iu.y >> 16);
    uint2 ou;
    ou.x = (unsigned int)f2bf(r0) | ((unsigned int)f2bf(r1) << 16);
    ou.y = (unsigned int)f2bf(r2) | ((unsigned int)f2bf(r3) << 16);
    ((uint2*)out)[i] = ou;
}

// ---------------------------------------------------------------------------
// Poincare expmap0 factor per node (wave/node)
// ---------------------------------------------------------------------------
__global__ __launch_bounds__(256) void pfac_k(const unsigned short* __restrict__ h,
                                              float* __restrict__ f, int M)
{
    int v = (blockIdx.x * blockDim.x + threadIdx.x) >> 6;
    int l = threadIdx.x & 63;
    if (v >= M) return;
    const unsigned short* r = h + (size_t)v * 96;
    float x1 = bf2f(r[l]);
    float x2 = (l < 32) ? bf2f(r[64 + l]) : 0.f;
    float q = x1 * x1 + x2 * x2;
    #pragma unroll
    for (int off = 32; off > 0; off >>= 1) q += __shfl_down(q, off);
    if (l == 0) {
        float n = fmaxf(sqrtf(q), 1e-15f);
        f[v] = tanhf(n) / n;
    }
}

// ---------------------------------------------------------------------------
// Graph mean-pool: register-accumulate per thread, flush on graph change.
// Replaces LDS-atomic version (83 us latency-bound: 98 blocks x 256 serial
// LDS-atomic iterations, 3% occupancy). batch sorted -> ~1-2 flushes/thread.
// 782 blocks x 32 iter of pure load+fma; global atomics ~195k over 6144 addrs.
// ---------------------------------------------------------------------------
__global__ __launch_bounds__(192) void pool_k(const unsigned short* __restrict__ h,
                                              const float* __restrict__ f,
                                              const int* __restrict__ batch,
                                              float* __restrict__ pooled,
                                              float* __restrict__ gcnt, int M)
{
    int c    = threadIdx.x % 96;
    int half = threadIdx.x / 96;
    int base = blockIdx.x * 64;
    int rend = min(base + 64, M);
    float acc = 0.f, cnt = 0.f;
    int curg = -1;
    for (int r = base + half; r < rend; r += 2) {
        int g = batch[r];
        if (g != curg) {
            if (curg >= 0) {
                atomicAdd(&pooled[curg * 96 + c], acc);
                if (c == 0) atomicAdd(&gcnt[curg], cnt);
            }
            acc = 0.f; cnt = 0.f; curg = g;
        }
        acc = fmaf(bf2f(h[(size_t)r * 96 + c]), f[r], acc);
        cnt += 1.f;
    }
    if (curg >= 0) {
        atomicAdd(&pooled[curg * 96 + c], acc);
        if (c == 0) atomicAdd(&gcnt[curg], cnt);
    }
}

// ---------------------------------------------------------------------------
// Head: one block per graph. pooled/cnt -> fc3+lrelu -> fc4 -> out.
// ---------------------------------------------------------------------------
__global__ __launch_bounds__(64) void head_k(const float* __restrict__ pooled,
                                             const float* __restrict__ gcnt,
                                             const void* __restrict__ w3,
                                             const void* __restrict__ b3,
                                             const void* __restrict__ w4,
                                             const void* __restrict__ b4,
                                             const int* __restrict__ dflag,
                                             void* __restrict__ outv)
{
    int g = blockIdx.x;
    int t = threadIdx.x;
    int f32 = dflag[0];
    __shared__ float p[96];
    __shared__ float o[48];
    float inv = 1.0f / fmaxf(gcnt[g], 1.0f);
    for (int c = t; c < 96; c += 64) p[c] = pooled[g * 96 + c] * inv;
    __syncthreads();
    if (t < 48) {
        float a = ldf(b3, t, f32);
        #pragma unroll
        for (int c = 0; c < 96; c++) a = fmaf(p[c], ldf(w3, (size_t)c * 48 + t, f32), a);
        o[t] = lrelu01(a);
    }
    __syncthreads();
    if (t < 4) {
        float a = ldf(b4, t, f32);
        #pragma unroll
        for (int j = 0; j < 48; j++) a = fmaf(o[j], ldf(w4, j * 4 + t, f32), a);
        if (f32) ((float*)outv)[g * 4 + t] = a;
        else     ((unsigned short*)outv)[g * 4 + t] = f2bf(a);
    }
}

// ---------------------------------------------------------------------------
// CSR construction (col stored as uint16 — node ids < 65536)
// ---------------------------------------------------------------------------
__global__ __launch_bounds__(256) void count_k(const int* __restrict__ ei,
                                               int* __restrict__ cnt)
{
    int e = blockIdx.x * 256 + threadIdx.x;
    if (e >= ET) return;
    int dstv = (e < N_EDGES) ? ei[N_EDGES + e] : (e - N_EDGES);
    atomicAdd(&cnt[dstv], 1);
}

__global__ __launch_bounds__(1024) void scan1_k(const int* __restrict__ cnt,
                                                int* __restrict__ rp,
                                                int* __restrict__ bsum, int n)
{
    __shared__ int sd[1024];
    int i = blockIdx.x * 1024 + threadIdx.x;
    int v = (i < n) ? cnt[i] : 0;
    sd[threadIdx.x] = v;
    __syncthreads();
    for (int off = 1; off < 1024; off <<= 1) {
        int t = 0;
        if (threadIdx.x >= off) t = sd[threadIdx.x - off];
        __syncthreads();
        if (threadIdx.x >= off) sd[threadIdx.x] += t;
        __syncthreads();
    }
    if (i < n) rp[i + 1] = sd[threadIdx.x];
    if (threadIdx.x == 1023) bsum[blockIdx.x] = sd[1023];
}

__global__ void scan2_k(int* __restrict__ bsum, int nb)
{
    if (blockIdx.x == 0 && threadIdx.x == 0) {
        int s = 0;
        for (int i = 0; i < nb; i++) { int t = bsum[i]; bsum[i] = s; s += t; }
    }
}

__global__ __launch_bounds__(1024) void scan3_k(int* __restrict__ rp,
                                                const int* __restrict__ bsum, int n)
{
    int i = blockIdx.x * 1024 + threadIdx.x;
    if (i < n) rp[i + 1] += bsum[blockIdx.x];
    if (i == 0) rp[0] = 0;
}

__global__ __launch_bounds__(256) void scatter_k(const int* __restrict__ ei,
                                                 const int* __restrict__ rp,
                                                 int* __restrict__ fill,
                                                 unsigned short* __restrict__ col)
{
    int e = blockIdx.x * 256 + threadIdx.x;
    if (e >= ET) return;
    int srcv, dstv;
    if (e < N_EDGES) { srcv = ei[e]; dstv = ei[N_EDGES + e]; }
    else             { srcv = dstv = e - N_EDGES; }
    int p = rp[dstv] + atomicAdd(&fill[dstv], 1);
    col[p] = (unsigned short)srcv;
}

// ---------------------------------------------------------------------------
extern "C" void kernel_launch(void* const* d_in, const int* in_sizes, int n_in,
                              void* d_out, int out_size, void* d_ws, size_t ws_size,
                              hipStream_t stream)
{
    const void* x     = d_in[0];
    const int*  ei    = (const int*)d_in[1];
    const int*  batch = (const int*)d_in[2];
    const void* embW  = d_in[3];
    const void* embB  = d_in[4];
    const void* convW[3]  = { d_in[5],  d_in[9],  d_in[13] };
    const void* convAs[3] = { d_in[6],  d_in[10], d_in[14] };
    const void* convAd[3] = { d_in[7],  d_in[11], d_in[15] };
    const void* convB[3]  = { d_in[8],  d_in[12], d_in[16] };
    const void* fcW[2]    = { d_in[17], d_in[19] };
    const void* fcB[2]    = { d_in[18], d_in[20] };
    const void* bnG[3]    = { d_in[21], d_in[23], d_in[25] };
    const void* bnB[3]    = { d_in[22], d_in[24], d_in[26] };
    const void* fc3W = d_in[27];
    const void* fc3b = d_in[28];
    const void* fc4W = d_in[29];
    const void* fc4b = d_in[30];

    // ---- workspace layout (total ≈ 31.5 MiB) ----
    char* wp_ = (char*)d_ws;
    auto alloc = [&](size_t b) { char* p = wp_; wp_ += (b + 255) & ~(size_t)255; return p; };
    int*   dflag = (int*)alloc(256);
    unsigned short* ident = (unsigned short*)alloc((size_t)N_NODES * H * 2);
    unsigned short* hA    = (unsigned short*)alloc((size_t)N_NODES * H * 2);
    unsigned short* hB    = (unsigned short*)alloc((size_t)N_NODES * H * 2);
    float* s_sc  = (float*)alloc((size_t)N_NODES * 4);
    float* d_sc  = (float*)alloc((size_t)N_NODES * 4);
    float* fvec  = (float*)alloc((size_t)N_NODES * 4);
    float* bnsum = (float*)alloc(192 * 4);
    float* coef  = (float*)alloc(192 * 4);
    float* pooled= (float*)alloc((NG * H + NG) * 4);
    float* gcnt  = pooled + NG * H;
    int*   rowptr= (int*)alloc((size_t)(N_NODES + 1) * 4);
    int*   cnt   = (int*)alloc((size_t)N_NODES * 4);
    unsigned short* col = (unsigned short*)alloc((size_t)ET * 2);
    int*   bsum  = (int*)alloc(64 * 4);

    const int NB = (N_NODES + 1023) / 1024;      // 49 scan blocks
    const int GE = (ET + 255) / 256;             // edge-parallel grid
    const int GM = (N_NODES + 63) / 64;          // gemm grid
    const int GW = (N_NODES * 64 + 255) / 256;   // wave-per-node grid
    const int N4 = N_NODES * H / 4;

    // ---- dtype detect ----
    detect_k<<<1, 64, 0, stream>>>((const unsigned short*)x, dflag);

    // ---- CSR build ----
    hipMemsetAsync(cnt, 0, (size_t)N_NODES * 4, stream);
    count_k<<<GE, 256, 0, stream>>>(ei, cnt);
    scan1_k<<<NB, 1024, 0, stream>>>(cnt, rowptr, bsum, N_NODES);
    scan2_k<<<1, 64, 0, stream>>>(bsum, NB);
    scan3_k<<<NB, 1024, 0, stream>>>(rowptr, bsum, N_NODES);
    hipMemsetAsync(cnt, 0, (size_t)N_NODES * 4, stream);
    scatter_k<<<GE, 256, 0, stream>>>(ei, rowptr, cnt, col);

    // ---- embed: h = lrelu(x @ embW + embB), identity = h ----
    gemm_k<2, 0><<<GM, 256, 0, stream>>>(x, embW, embB, dflag, hA, ident, N_NODES, F_IN);

    unsigned short* hcur = hA;
    unsigned short* htmp = hB;

    for (int l = 0; l < 3; l++) {
        // h2 = h @ convW
        gemm_k<0, 1><<<GM, 256, 0, stream>>>(hcur, convW[l], nullptr, dflag, htmp, nullptr, N_NODES, H);
        sd_k<<<GW, 256, 0, stream>>>(htmp, convAs[l], convAd[l], dflag, s_sc, d_sc, N_NODES);
        agg_k<<<GW, 256, 0, stream>>>(htmp, s_sc, d_sc, rowptr, col, convB[l], dflag, hcur, N_NODES);
        // BN + lrelu + residual
        hipMemsetAsync(bnsum, 0, 192 * 4, stream);
        bnstats_k<<<256, 192, 0, stream>>>(hcur, bnsum, N_NODES);
        bncoef_k<<<1, 128, 0, stream>>>(bnsum, bnG[l], bnB[l], dflag, coef);
        bnapply_k<<<(N4 + 255) / 256, 256, 0, stream>>>(hcur, coef, ident, hcur, N4);
        if (l < 2) {
            gemm_k<1, 1><<<GM, 256, 0, stream>>>(hcur, fcW[l], fcB[l], dflag, htmp, nullptr, N_NODES, H);
            unsigned short* t = hcur; hcur = htmp; htmp = t;
        }
    }

    // ---- Poincare + pooling + head ----
    pfac_k<<<GW, 256, 0, stream>>>(hcur, fvec, N_NODES);
    hipMemsetAsync(pooled, 0, (size_t)(NG * H + NG) * 4, stream);
    pool_k<<<(N_NODES + 63) / 64, 192, 0, stream>>>(hcur, fvec, batch, pooled, gcnt, N_NODES);
    head_k<<<NG, 64, 0, stream>>>(pooled, gcnt, fc3W, fc3b, fc4W, fc4b, dflag, d_out);
}

// Round 6
// 782.489 us; speedup vs baseline: 1.6273x; 1.0490x over previous
//
#include <hip/hip_runtime.h>
#include <hip/hip_bf16.h>

#define DEVINL __device__ __forceinline__

constexpr int N_NODES = 50000;
constexpr int N_EDGES = 800000;
constexpr int ET      = N_EDGES + N_NODES;   // edges + self loops
constexpr int F_IN    = 256;
constexpr int H       = 96;
constexpr int NG      = 64;                  // graphs
constexpr float BN_EPS = 1e-5f;

DEVINL float bf2f(unsigned int u) {
    union { unsigned int i; float f; } c; c.i = u << 16; return c.f;
}
DEVINL unsigned short f2bf(float f) {
    union { float f; unsigned int i; } c; c.f = f;
    unsigned int x = c.i;
    return (unsigned short)((x + 0x7fffu + ((x >> 16) & 1u)) >> 16);
}
DEVINL float lrelu01(float v) { return v >= 0.f ? v : 0.01f * v; }
// dtype-flag aware scalar load of a "float tensor" input
DEVINL float ldf(const void* p, size_t i, int f32) {
    return f32 ? ((const float*)p)[i] : bf2f(((const unsigned short*)p)[i]);
}

// ---------------------------------------------------------------------------
// dtype detection: interpret first 64 shorts of x as bf16. fp32-backed data
// has random mantissa shorts -> many |v|>1e4/NaN. bf16-backed -> none.
// ---------------------------------------------------------------------------
__global__ void detect_k(const unsigned short* __restrict__ x, int* __restrict__ flag)
{
    int l = threadIdx.x;
    float f = bf2f(x[l]);
    bool huge = !(fabsf(f) <= 1e4f);          // catches NaN/Inf too
    unsigned long long m = __ballot(huge);
    if (l == 0) flag[0] = (__popcll(m) >= 8) ? 1 : 0;   // 1 = fp32, 0 = bf16
}

// ---------------------------------------------------------------------------
// GEMM: out[M,96] = A[M,K] @ W[K,96]  (A,W per dflag; out bf16; fp32 accum)
// EPI: 0 = plain, 1 = lrelu(acc+bias), 2 = lrelu(acc+bias) -> out and out2
// AWS: 1 if A lives in workspace (always bf16), 0 if A is an input (per dflag)
// ---------------------------------------------------------------------------
template<int EPI, int AWS>
__global__ __launch_bounds__(256) void gemm_k(
    const void* __restrict__ Ap, const void* __restrict__ Wp,
    const void* __restrict__ bp, const int* __restrict__ dflag,
    unsigned short* __restrict__ out, unsigned short* __restrict__ out2,
    int M, int K)
{
    __shared__ float As[64][36];
    __shared__ float Ws[32][96];
    const int f32  = AWS ? 0 : dflag[0];
    const int wf32 = dflag[0];
    const int tid  = threadIdx.x;
    const int row0 = blockIdx.x * 64;
    const int tm0  = (tid >> 4) << 2;   // 0..60
    const int tn0  = (tid & 15) * 6;    // 0..90
    const int lm   = tid >> 2;          // load row 0..63
    const int lk   = (tid & 3) << 3;    // 0,8,16,24
    const int lr   = row0 + lm;

    float acc[4][6] = {};

    for (int kc = 0; kc < K; kc += 32) {
        if (lr < M) {
            if (f32) {
                const float* A = (const float*)Ap;
                const float4* p = (const float4*)(A + (size_t)lr * K + kc + lk);
                float4 v0 = p[0], v1 = p[1];
                *(float4*)&As[lm][lk]     = v0;
                *(float4*)&As[lm][lk + 4] = v1;
            } else {
                const unsigned short* A = (const unsigned short*)Ap;
                uint4 u = *(const uint4*)(A + (size_t)lr * K + kc + lk);
                *(float4*)&As[lm][lk]     = make_float4(bf2f(u.x & 0xffff), bf2f(u.x >> 16),
                                                        bf2f(u.y & 0xffff), bf2f(u.y >> 16));
                *(float4*)&As[lm][lk + 4] = make_float4(bf2f(u.z & 0xffff), bf2f(u.z >> 16),
                                                        bf2f(u.w & 0xffff), bf2f(u.w >> 16));
            }
        } else {
            *(float4*)&As[lm][lk]     = make_float4(0.f, 0.f, 0.f, 0.f);
            *(float4*)&As[lm][lk + 4] = make_float4(0.f, 0.f, 0.f, 0.f);
        }

        #pragma unroll
        for (int p = 0; p < 3; p++) {
            int f = p * 1024 + tid * 4;
            int k = f / 96, j = f - k * 96;   // j is a multiple of 4
            if (wf32) {
                const float* W = (const float*)Wp;
                *(float4*)&Ws[k][j] = *(const float4*)(W + (size_t)(kc + k) * 96 + j);
            } else {
                const unsigned short* W = (const unsigned short*)Wp;
                uint2 u = *(const uint2*)(W + (size_t)(kc + k) * 96 + j);
                *(float4*)&Ws[k][j] = make_float4(bf2f(u.x & 0xffff), bf2f(u.x >> 16),
                                                  bf2f(u.y & 0xffff), bf2f(u.y >> 16));
            }
        }
        __syncthreads();

        #pragma unroll
        for (int kk = 0; kk < 32; kk++) {
            float aa[4];
            aa[0] = As[tm0 + 0][kk]; aa[1] = As[tm0 + 1][kk];
            aa[2] = As[tm0 + 2][kk]; aa[3] = As[tm0 + 3][kk];
            const float2* wp2 = (const float2*)&Ws[kk][tn0];
            float2 w01 = wp2[0], w23 = wp2[1], w45 = wp2[2];
            float wv[6] = { w01.x, w01.y, w23.x, w23.y, w45.x, w45.y };
            #pragma unroll
            for (int i = 0; i < 4; i++)
                #pragma unroll
                for (int j = 0; j < 6; j++)
                    acc[i][j] = fmaf(aa[i], wv[j], acc[i][j]);
        }
        __syncthreads();
    }

    float bv[6];
    if (EPI > 0) {
        #pragma unroll
        for (int j = 0; j < 6; j++) bv[j] = ldf(bp, tn0 + j, wf32);
    }
    #pragma unroll
    for (int i = 0; i < 4; i++) {
        int r = row0 + tm0 + i;
        if (r >= M) continue;
        size_t o = (size_t)r * 96 + tn0;   // even -> 4B-aligned bf16 addr
        unsigned int pk[3];
        #pragma unroll
        for (int j = 0; j < 3; j++) {
            float v0 = acc[i][2 * j], v1 = acc[i][2 * j + 1];
            if (EPI > 0) {
                v0 = lrelu01(v0 + bv[2 * j]);
                v1 = lrelu01(v1 + bv[2 * j + 1]);
            }
            pk[j] = (unsigned int)f2bf(v0) | ((unsigned int)f2bf(v1) << 16);
        }
        unsigned int* po = (unsigned int*)(out + o);
        po[0] = pk[0]; po[1] = pk[1]; po[2] = pk[2];
        if (EPI == 2) {
            unsigned int* po2 = (unsigned int*)(out2 + o);
            po2[0] = pk[0]; po2[1] = pk[1]; po2[2] = pk[2];
        }
    }
}

// ---------------------------------------------------------------------------
// Per-node attention scalars: s[v] = h2[v]·a_s, d[v] = h2[v]·a_d (wave/node)
// ---------------------------------------------------------------------------
__global__ __launch_bounds__(256) void sd_k(
    const unsigned short* __restrict__ h2, const void* __restrict__ as_,
    const void* __restrict__ ad_, const int* __restrict__ dflag,
    float* __restrict__ s, float* __restrict__ d, int M)
{
    int f32 = dflag[0];
    int v = (blockIdx.x * blockDim.x + threadIdx.x) >> 6;
    int l = threadIdx.x & 63;
    if (v >= M) return;
    const unsigned short* r = h2 + (size_t)v * 96;
    float x1 = bf2f(r[l]);
    float x2 = (l < 32) ? bf2f(r[64 + l]) : 0.f;
    float as1 = ldf(as_, l, f32),  ad1 = ldf(ad_, l, f32);
    float as2 = (l < 32) ? ldf(as_, 64 + l, f32) : 0.f;
    float ad2 = (l < 32) ? ldf(ad_, 64 + l, f32) : 0.f;
    float ps = x1 * as1 + x2 * as2;
    float pd = x1 * ad1 + x2 * ad2;
    #pragma unroll
    for (int off = 32; off > 0; off >>= 1) {
        ps += __shfl_down(ps, off);
        pd += __shfl_down(pd, off);
    }
    if (l == 0) { s[v] = ps; d[v] = pd; }
}

// ---------------------------------------------------------------------------
// GAT aggregation, one wave per destination node over CSR (h2 bf16).
// Fast path (deg<=64, always hit for Poisson(17) degrees): col + s gathered
// ONCE into registers; softmax via shfl; feature gather packed (lane l<48
// handles feature pair 2l,2l+1 -> one uint load per edge, 192B coalesced).
// Replaces the 3-pass version that re-gathered s[col[..]] three times.
// ---------------------------------------------------------------------------
__global__ __launch_bounds__(256) void agg_k(
    const unsigned short* __restrict__ h2, const float* __restrict__ s,
    const float* __restrict__ d, const int* __restrict__ rowptr,
    const unsigned short* __restrict__ col, const void* __restrict__ bias,
    const int* __restrict__ dflag, unsigned short* __restrict__ out, int M)
{
    int f32 = dflag[0];
    int v = (blockIdx.x * blockDim.x + threadIdx.x) >> 6;
    int l = threadIdx.x & 63;
    if (v >= M) return;
    int st = rowptr[v], en = rowptr[v + 1];
    int deg = en - st;
    float dv = d[v];

    if (deg > 0 && deg <= 64) {
        int u = 0; float e = -1e30f;
        if (l < deg) {
            u = col[st + l];
            float t = s[u] + dv;
            e = t >= 0.f ? t : 0.2f * t;
        }
        float lm = e;
        #pragma unroll
        for (int off = 32; off > 0; off >>= 1) lm = fmaxf(lm, __shfl_xor(lm, off));
        float w = (l < deg) ? __expf(e - lm) : 0.f;
        float ls = w;
        #pragma unroll
        for (int off = 32; off > 0; off >>= 1) ls += __shfl_xor(ls, off);
        float rden = 1.0f / ls;

        bool hw = (l < 48);
        int  c2 = 2 * l;
        float a0 = 0.f, a1 = 0.f;
        for (int j = 0; j < deg; j++) {
            int   uj = __shfl(u, j);
            float wj = __shfl(w, j);
            if (hw) {
                unsigned int hv = *(const unsigned int*)(h2 + (size_t)uj * 96 + c2);
                a0 = fmaf(wj, bf2f(hv & 0xffff), a0);
                a1 = fmaf(wj, bf2f(hv >> 16),    a1);
            }
        }
        if (hw) {
            float b0 = ldf(bias, c2,     f32);
            float b1 = ldf(bias, c2 + 1, f32);
            unsigned int o = (unsigned int)f2bf(a0 * rden + b0)
                           | ((unsigned int)f2bf(a1 * rden + b1) << 16);
            *(unsigned int*)(out + (size_t)v * 96 + c2) = o;
        }
        return;
    }

    // ---- general fallback (deg == 0 or deg > 64) ----
    int  c0 = l, c1 = 64 + l;
    bool has2 = (l < 32);
    if (deg <= 0) {
        out[(size_t)v * 96 + c0] = f2bf(ldf(bias, c0, f32));
        if (has2) out[(size_t)v * 96 + c1] = f2bf(ldf(bias, c1, f32));
        return;
    }
    float lm = -1e30f;
    for (int i = l; i < deg; i += 64) {
        float e = s[col[st + i]] + dv;
        e = e >= 0.f ? e : 0.2f * e;
        lm = fmaxf(lm, e);
    }
    #pragma unroll
    for (int off = 32; off > 0; off >>= 1) lm = fmaxf(lm, __shfl_xor(lm, off));
    float ls = 0.f;
    for (int i = l; i < deg; i += 64) {
        float e = s[col[st + i]] + dv;
        e = e >= 0.f ? e : 0.2f * e;
        ls += __expf(e - lm);
    }
    #pragma unroll
    for (int off = 32; off > 0; off >>= 1) ls += __shfl_xor(ls, off);
    float rden = 1.0f / ls;
    float acc0 = 0.f, acc1 = 0.f;
    for (int base = 0; base < deg; base += 64) {
        int i = base + l;
        int u = 0; float w = 0.f;
        if (i < deg) {
            u = col[st + i];
            float e = s[u] + dv;
            e = e >= 0.f ? e : 0.2f * e;
            w = __expf(e - lm);
        }
        int cl = min(64, deg - base);
        for (int j = 0; j < cl; j++) {
            int   uj = __shfl(u, j);
            float wj = __shfl(w, j);
            const unsigned short* hr = h2 + (size_t)uj * 96;
            acc0 = fmaf(wj, bf2f(hr[c0]), acc0);
            if (has2) acc1 = fmaf(wj, bf2f(hr[c1]), acc1);
        }
    }
    out[(size_t)v * 96 + c0] = f2bf(acc0 * rden + ldf(bias, c0, f32));
    if (has2) out[(size_t)v * 96 + c1] = f2bf(acc1 * rden + ldf(bias, c1, f32));
}

// ---------------------------------------------------------------------------
// BatchNorm statistics / coefficients / apply(+residual+lrelu)
// ---------------------------------------------------------------------------
__global__ __launch_bounds__(192) void bnstats_k(const unsigned short* __restrict__ x,
                                                 float* __restrict__ sums, int M)
{
    int c  = threadIdx.x % 96;
    int g2 = threadIdx.x / 96;
    float s = 0.f, q = 0.f;
    for (int r = blockIdx.x * 2 + g2; r < M; r += gridDim.x * 2) {
        float v = bf2f(x[(size_t)r * 96 + c]);
        s += v; q += v * v;
    }
    __shared__ float lsd[192], lqd[192];
    lsd[threadIdx.x] = s; lqd[threadIdx.x] = q;
    __syncthreads();
    if (g2 == 0) {
        atomicAdd(&sums[c],      s + lsd[threadIdx.x + 96]);
        atomicAdd(&sums[96 + c], q + lqd[threadIdx.x + 96]);
    }
}

__global__ void bncoef_k(const float* __restrict__ sums,
                         const void* __restrict__ g_,
                         const void* __restrict__ b_,
                         const int* __restrict__ dflag,
                         float* __restrict__ coef)
{
    int c = threadIdx.x;
    if (c >= 96) return;
    int f32 = dflag[0];
    float mu  = sums[c] * (1.f / N_NODES);
    float var = sums[96 + c] * (1.f / N_NODES) - mu * mu;
    float rinv = 1.0f / sqrtf(var + BN_EPS);
    float sc = ldf(g_, c, f32) * rinv;
    coef[c]      = sc;
    coef[96 + c] = ldf(b_, c, f32) - mu * sc;
}

// x/out may alias (in-place): no __restrict__ on those.
__global__ __launch_bounds__(256) void bnapply_k(const unsigned short* x,
                                                 const float* __restrict__ coef,
                                                 const unsigned short* __restrict__ iden,
                                                 unsigned short* out, int n4)
{
    int i = blockIdx.x * blockDim.x + threadIdx.x;
    if (i >= n4) return;
    int c4 = (i % 24) * 4;
    uint2 xu = ((const uint2*)x)[i];
    uint2 iu = ((const uint2*)iden)[i];
    float4 sc = *(const float4*)&coef[c4];
    float4 sh = *(const float4*)&coef[96 + c4];
    float r0 = lrelu01(bf2f(xu.x & 0xffff) * sc.x + sh.x) + bf2f(iu.x & 0xffff);
    float r1 = lrelu01(bf2f(xu.x >> 16)    * sc.y + sh.y) + bf2f(iu.x >> 16);
    float r2 = lrelu01(bf2f(xu.y & 0xffff) * sc.z + sh.z) + bf2f(iu.y & 0xffff);
    float r3 = lrelu01(bf2f(xu.y >> 16)    * sc.w + sh.w) + bf2f(iu.y >> 16);
    uint2 ou;
    ou.x = (unsigned int)f2bf(r0) | ((unsigned int)f2bf(r1) << 16);
    ou.y = (unsigned int)f2bf(r2) | ((unsigned int)f2bf(r3) << 16);
    ((uint2*)out)[i] = ou;
}

// ---------------------------------------------------------------------------
// Poincare expmap0 factor per node (wave/node)
// ---------------------------------------------------------------------------
__global__ __launch_bounds__(256) void pfac_k(const unsigned short* __restrict__ h,
                                              float* __restrict__ f, int M)
{
    int v = (blockIdx.x * blockDim.x + threadIdx.x) >> 6;
    int l = threadIdx.x & 63;
    if (v >= M) return;
    const unsigned short* r = h + (size_t)v * 96;
    float x1 = bf2f(r[l]);
    float x2 = (l < 32) ? bf2f(r[64 + l]) : 0.f;
    float q = x1 * x1 + x2 * x2;
    #pragma unroll
    for (int off = 32; off > 0; off >>= 1) q += __shfl_down(q, off);
    if (l == 0) {
        float n = fmaxf(sqrtf(q), 1e-15f);
        f[v] = tanhf(n) / n;
    }
}

// ---------------------------------------------------------------------------
// Graph mean-pool: register-accumulate per thread, flush on graph change.
// ---------------------------------------------------------------------------
__global__ __launch_bounds__(192) void pool_k(const unsigned short* __restrict__ h,
                                              const float* __restrict__ f,
                                              const int* __restrict__ batch,
                                              float* __restrict__ pooled,
                                              float* __restrict__ gcnt, int M)
{
    int c    = threadIdx.x % 96;
    int half = threadIdx.x / 96;
    int base = blockIdx.x * 64;
    int rend = min(base + 64, M);
    float acc = 0.f, cnt = 0.f;
    int curg = -1;
    for (int r = base + half; r < rend; r += 2) {
        int g = batch[r];
        if (g != curg) {
            if (curg >= 0) {
                atomicAdd(&pooled[curg * 96 + c], acc);
                if (c == 0) atomicAdd(&gcnt[curg], cnt);
            }
            acc = 0.f; cnt = 0.f; curg = g;
        }
        acc = fmaf(bf2f(h[(size_t)r * 96 + c]), f[r], acc);
        cnt += 1.f;
    }
    if (curg >= 0) {
        atomicAdd(&pooled[curg * 96 + c], acc);
        if (c == 0) atomicAdd(&gcnt[curg], cnt);
    }
}

// ---------------------------------------------------------------------------
// Head: one block per graph. pooled/cnt -> fc3+lrelu -> fc4 -> out.
// ---------------------------------------------------------------------------
__global__ __launch_bounds__(64) void head_k(const float* __restrict__ pooled,
                                             const float* __restrict__ gcnt,
                                             const void* __restrict__ w3,
                                             const void* __restrict__ b3,
                                             const void* __restrict__ w4,
                                             const void* __restrict__ b4,
                                             const int* __restrict__ dflag,
                                             void* __restrict__ outv)
{
    int g = blockIdx.x;
    int t = threadIdx.x;
    int f32 = dflag[0];
    __shared__ float p[96];
    __shared__ float o[48];
    float inv = 1.0f / fmaxf(gcnt[g], 1.0f);
    for (int c = t; c < 96; c += 64) p[c] = pooled[g * 96 + c] * inv;
    __syncthreads();
    if (t < 48) {
        float a = ldf(b3, t, f32);
        #pragma unroll
        for (int c = 0; c < 96; c++) a = fmaf(p[c], ldf(w3, (size_t)c * 48 + t, f32), a);
        o[t] = lrelu01(a);
    }
    __syncthreads();
    if (t < 4) {
        float a = ldf(b4, t, f32);
        #pragma unroll
        for (int j = 0; j < 48; j++) a = fmaf(o[j], ldf(w4, j * 4 + t, f32), a);
        if (f32) ((float*)outv)[g * 4 + t] = a;
        else     ((unsigned short*)outv)[g * 4 + t] = f2bf(a);
    }
}

// ---------------------------------------------------------------------------
// CSR construction (col stored as uint16 — node ids < 65536)
// ---------------------------------------------------------------------------
__global__ __launch_bounds__(256) void count_k(const int* __restrict__ ei,
                                               int* __restrict__ cnt)
{
    int e = blockIdx.x * 256 + threadIdx.x;
    if (e >= ET) return;
    int dstv = (e < N_EDGES) ? ei[N_EDGES + e] : (e - N_EDGES);
    atomicAdd(&cnt[dstv], 1);
}

__global__ __launch_bounds__(1024) void scan1_k(const int* __restrict__ cnt,
                                                int* __restrict__ rp,
                                                int* __restrict__ bsum, int n)
{
    __shared__ int sd[1024];
    int i = blockIdx.x * 1024 + threadIdx.x;
    int v = (i < n) ? cnt[i] : 0;
    sd[threadIdx.x] = v;
    __syncthreads();
    for (int off = 1; off < 1024; off <<= 1) {
        int t = 0;
        if (threadIdx.x >= off) t = sd[threadIdx.x - off];
        __syncthreads();
        if (threadIdx.x >= off) sd[threadIdx.x] += t;
        __syncthreads();
    }
    if (i < n) rp[i + 1] = sd[threadIdx.x];
    if (threadIdx.x == 1023) bsum[blockIdx.x] = sd[1023];
}

__global__ void scan2_k(int* __restrict__ bsum, int nb)
{
    if (blockIdx.x == 0 && threadIdx.x == 0) {
        int s = 0;
        for (int i = 0; i < nb; i++) { int t = bsum[i]; bsum[i] = s; s += t; }
    }
}

__global__ __launch_bounds__(1024) void scan3_k(int* __restrict__ rp,
                                                const int* __restrict__ bsum, int n)
{
    int i = blockIdx.x * 1024 + threadIdx.x;
    if (i < n) rp[i + 1] += bsum[blockIdx.x];
    if (i == 0) rp[0] = 0;
}

__global__ __launch_bounds__(256) void scatter_k(const int* __restrict__ ei,
                                                 const int* __restrict__ rp,
                                                 int* __restrict__ fill,
                                                 unsigned short* __restrict__ col)
{
    int e = blockIdx.x * 256 + threadIdx.x;
    if (e >= ET) return;
    int srcv, dstv;
    if (e < N_EDGES) { srcv = ei[e]; dstv = ei[N_EDGES + e]; }
    else             { srcv = dstv = e - N_EDGES; }
    int p = rp[dstv] + atomicAdd(&fill[dstv], 1);
    col[p] = (unsigned short)srcv;
}

// ---------------------------------------------------------------------------
extern "C" void kernel_launch(void* const* d_in, const int* in_sizes, int n_in,
                              void* d_out, int out_size, void* d_ws, size_t ws_size,
                              hipStream_t stream)
{
    const void* x     = d_in[0];
    const int*  ei    = (const int*)d_in[1];
    const int*  batch = (const int*)d_in[2];
    const void* embW  = d_in[3];
    const void* embB  = d_in[4];
    const void* convW[3]  = { d_in[5],  d_in[9],  d_in[13] };
    const void* convAs[3] = { d_in[6],  d_in[10], d_in[14] };
    const void* convAd[3] = { d_in[7],  d_in[11], d_in[15] };
    const void* convB[3]  = { d_in[8],  d_in[12], d_in[16] };
    const void* fcW[2]    = { d_in[17], d_in[19] };
    const void* fcB[2]    = { d_in[18], d_in[20] };
    const void* bnG[3]    = { d_in[21], d_in[23], d_in[25] };
    const void* bnB[3]    = { d_in[22], d_in[24], d_in[26] };
    const void* fc3W = d_in[27];
    const void* fc3b = d_in[28];
    const void* fc4W = d_in[29];
    const void* fc4b = d_in[30];

    // ---- workspace layout (total ≈ 31.5 MiB) ----
    char* wp_ = (char*)d_ws;
    auto alloc = [&](size_t b) { char* p = wp_; wp_ += (b + 255) & ~(size_t)255; return p; };
    int*   dflag = (int*)alloc(256);
    unsigned short* ident = (unsigned short*)alloc((size_t)N_NODES * H * 2);
    unsigned short* hA    = (unsigned short*)alloc((size_t)N_NODES * H * 2);
    unsigned short* hB    = (unsigned short*)alloc((size_t)N_NODES * H * 2);
    float* s_sc  = (float*)alloc((size_t)N_NODES * 4);
    float* d_sc  = (float*)alloc((size_t)N_NODES * 4);
    float* fvec  = (float*)alloc((size_t)N_NODES * 4);
    float* bnsum = (float*)alloc(192 * 4);
    float* coef  = (float*)alloc(192 * 4);
    float* pooled= (float*)alloc((NG * H + NG) * 4);
    float* gcnt  = pooled + NG * H;
    int*   rowptr= (int*)alloc((size_t)(N_NODES + 1) * 4);
    int*   cnt   = (int*)alloc((size_t)N_NODES * 4);
    unsigned short* col = (unsigned short*)alloc((size_t)ET * 2);
    int*   bsum  = (int*)alloc(64 * 4);

    const int NB = (N_NODES + 1023) / 1024;      // 49 scan blocks
    const int GE = (ET + 255) / 256;             // edge-parallel grid
    const int GM = (N_NODES + 63) / 64;          // gemm grid
    const int GW = (N_NODES * 64 + 255) / 256;   // wave-per-node grid
    const int N4 = N_NODES * H / 4;

    // ---- dtype detect ----
    detect_k<<<1, 64, 0, stream>>>((const unsigned short*)x, dflag);

    // ---- CSR build ----
    hipMemsetAsync(cnt, 0, (size_t)N_NODES * 4, stream);
    count_k<<<GE, 256, 0, stream>>>(ei, cnt);
    scan1_k<<<NB, 1024, 0, stream>>>(cnt, rowptr, bsum, N_NODES);
    scan2_k<<<1, 64, 0, stream>>>(bsum, NB);
    scan3_k<<<NB, 1024, 0, stream>>>(rowptr, bsum, N_NODES);
    hipMemsetAsync(cnt, 0, (size_t)N_NODES * 4, stream);
    scatter_k<<<GE, 256, 0, stream>>>(ei, rowptr, cnt, col);

    // ---- embed: h = lrelu(x @ embW + embB), identity = h ----
    gemm_k<2, 0><<<GM, 256, 0, stream>>>(x, embW, embB, dflag, hA, ident, N_NODES, F_IN);

    unsigned short* hcur = hA;
    unsigned short* htmp = hB;

    for (int l = 0; l < 3; l++) {
        // h2 = h @ convW
        gemm_k<0, 1><<<GM, 256, 0, stream>>>(hcur, convW[l], nullptr, dflag, htmp, nullptr, N_NODES, H);
        sd_k<<<GW, 256, 0, stream>>>(htmp, convAs[l], convAd[l], dflag, s_sc, d_sc, N_NODES);
        agg_k<<<GW, 256, 0, stream>>>(htmp, s_sc, d_sc, rowptr, col, convB[l], dflag, hcur, N_NODES);
        // BN + lrelu + residual
        hipMemsetAsync(bnsum, 0, 192 * 4, stream);
        bnstats_k<<<256, 192, 0, stream>>>(hcur, bnsum, N_NODES);
        bncoef_k<<<1, 128, 0, stream>>>(bnsum, bnG[l], bnB[l], dflag, coef);
        bnapply_k<<<(N4 + 255) / 256, 256, 0, stream>>>(hcur, coef, ident, hcur, N4);
        if (l < 2) {
            gemm_k<1, 1><<<GM, 256, 0, stream>>>(hcur, fcW[l], fcB[l], dflag, htmp, nullptr, N_NODES, H);
            unsigned short* t = hcur; hcur = htmp; htmp = t;
        }
    }

    // ---- Poincare + pooling + head ----
    pfac_k<<<GW, 256, 0, stream>>>(hcur, fvec, N_NODES);
    hipMemsetAsync(pooled, 0, (size_t)(NG * H + NG) * 4, stream);
    pool_k<<<(N_NODES + 63) / 64, 192, 0, stream>>>(hcur, fvec, batch, pooled, gcnt, N_NODES);
    head_k<<<NG, 64, 0, stream>>>(pooled, gcnt, fc3W, fc3b, fc4W, fc4b, dflag, d_out);
}

// Round 7
// 705.273 us; speedup vs baseline: 1.8055x; 1.1095x over previous
//
#include <hip/hip_runtime.h>
#include <hip/hip_bf16.h>

#define DEVINL __device__ __forceinline__

constexpr int N_NODES = 50000;
constexpr int N_EDGES = 800000;
constexpr int ET      = N_EDGES + N_NODES;   // edges + self loops
constexpr int F_IN    = 256;
constexpr int H       = 96;
constexpr int NG      = 64;                  // graphs
constexpr float BN_EPS = 1e-5f;

DEVINL float bf2f(unsigned int u) {
    union { unsigned int i; float f; } c; c.i = u << 16; return c.f;
}
DEVINL unsigned short f2bf(float f) {
    union { float f; unsigned int i; } c; c.f = f;
    unsigned int x = c.i;
    return (unsigned short)((x + 0x7fffu + ((x >> 16) & 1u)) >> 16);
}
DEVINL float lrelu01(float v) { return v >= 0.f ? v : 0.01f * v; }
// dtype-flag aware scalar load of a "float tensor" input
DEVINL float ldf(const void* p, size_t i, int f32) {
    return f32 ? ((const float*)p)[i] : bf2f(((const unsigned short*)p)[i]);
}

// ---------------------------------------------------------------------------
// dtype detection: interpret first 64 shorts of x as bf16. fp32-backed data
// has random mantissa shorts -> many |v|>1e4/NaN. bf16-backed -> none.
// ---------------------------------------------------------------------------
__global__ void detect_k(const unsigned short* __restrict__ x, int* __restrict__ flag)
{
    int l = threadIdx.x;
    float f = bf2f(x[l]);
    bool huge = !(fabsf(f) <= 1e4f);          // catches NaN/Inf too
    unsigned long long m = __ballot(huge);
    if (l == 0) flag[0] = (__popcll(m) >= 8) ? 1 : 0;   // 1 = fp32, 0 = bf16
}

// ---------------------------------------------------------------------------
// GEMM: out[M,96] = A[M,K] @ W[K,96]  (A,W per dflag; out bf16; fp32 accum)
// EPI: 0 = plain, 1 = lrelu(acc+bias), 2 = lrelu(acc+bias) -> out and out2
// AWS: 1 if A lives in workspace (always bf16), 0 if A is an input (per dflag)
// ---------------------------------------------------------------------------
template<int EPI, int AWS>
__global__ __launch_bounds__(256) void gemm_k(
    const void* __restrict__ Ap, const void* __restrict__ Wp,
    const void* __restrict__ bp, const int* __restrict__ dflag,
    unsigned short* __restrict__ out, unsigned short* __restrict__ out2,
    int M, int K)
{
    __shared__ float As[64][36];
    __shared__ float Ws[32][96];
    const int f32  = AWS ? 0 : dflag[0];
    const int wf32 = dflag[0];
    const int tid  = threadIdx.x;
    const int row0 = blockIdx.x * 64;
    const int tm0  = (tid >> 4) << 2;   // 0..60
    const int tn0  = (tid & 15) * 6;    // 0..90
    const int lm   = tid >> 2;          // load row 0..63
    const int lk   = (tid & 3) << 3;    // 0,8,16,24
    const int lr   = row0 + lm;

    float acc[4][6] = {};

    for (int kc = 0; kc < K; kc += 32) {
        if (lr < M) {
            if (f32) {
                const float* A = (const float*)Ap;
                const float4* p = (const float4*)(A + (size_t)lr * K + kc + lk);
                float4 v0 = p[0], v1 = p[1];
                *(float4*)&As[lm][lk]     = v0;
                *(float4*)&As[lm][lk + 4] = v1;
            } else {
                const unsigned short* A = (const unsigned short*)Ap;
                uint4 u = *(const uint4*)(A + (size_t)lr * K + kc + lk);
                *(float4*)&As[lm][lk]     = make_float4(bf2f(u.x & 0xffff), bf2f(u.x >> 16),
                                                        bf2f(u.y & 0xffff), bf2f(u.y >> 16));
                *(float4*)&As[lm][lk + 4] = make_float4(bf2f(u.z & 0xffff), bf2f(u.z >> 16),
                                                        bf2f(u.w & 0xffff), bf2f(u.w >> 16));
            }
        } else {
            *(float4*)&As[lm][lk]     = make_float4(0.f, 0.f, 0.f, 0.f);
            *(float4*)&As[lm][lk + 4] = make_float4(0.f, 0.f, 0.f, 0.f);
        }

        #pragma unroll
        for (int p = 0; p < 3; p++) {
            int f = p * 1024 + tid * 4;
            int k = f / 96, j = f - k * 96;   // j is a multiple of 4
            if (wf32) {
                const float* W = (const float*)Wp;
                *(float4*)&Ws[k][j] = *(const float4*)(W + (size_t)(kc + k) * 96 + j);
            } else {
                const unsigned short* W = (const unsigned short*)Wp;
                uint2 u = *(const uint2*)(W + (size_t)(kc + k) * 96 + j);
                *(float4*)&Ws[k][j] = make_float4(bf2f(u.x & 0xffff), bf2f(u.x >> 16),
                                                  bf2f(u.y & 0xffff), bf2f(u.y >> 16));
            }
        }
        __syncthreads();

        #pragma unroll
        for (int kk = 0; kk < 32; kk++) {
            float aa[4];
            aa[0] = As[tm0 + 0][kk]; aa[1] = As[tm0 + 1][kk];
            aa[2] = As[tm0 + 2][kk]; aa[3] = As[tm0 + 3][kk];
            const float2* wp2 = (const float2*)&Ws[kk][tn0];
            float2 w01 = wp2[0], w23 = wp2[1], w45 = wp2[2];
            float wv[6] = { w01.x, w01.y, w23.x, w23.y, w45.x, w45.y };
            #pragma unroll
            for (int i = 0; i < 4; i++)
                #pragma unroll
                for (int j = 0; j < 6; j++)
                    acc[i][j] = fmaf(aa[i], wv[j], acc[i][j]);
        }
        __syncthreads();
    }

    float bv[6];
    if (EPI > 0) {
        #pragma unroll
        for (int j = 0; j < 6; j++) bv[j] = ldf(bp, tn0 + j, wf32);
    }
    #pragma unroll
    for (int i = 0; i < 4; i++) {
        int r = row0 + tm0 + i;
        if (r >= M) continue;
        size_t o = (size_t)r * 96 + tn0;   // even -> 4B-aligned bf16 addr
        unsigned int pk[3];
        #pragma unroll
        for (int j = 0; j < 3; j++) {
            float v0 = acc[i][2 * j], v1 = acc[i][2 * j + 1];
            if (EPI > 0) {
                v0 = lrelu01(v0 + bv[2 * j]);
                v1 = lrelu01(v1 + bv[2 * j + 1]);
            }
            pk[j] = (unsigned int)f2bf(v0) | ((unsigned int)f2bf(v1) << 16);
        }
        unsigned int* po = (unsigned int*)(out + o);
        po[0] = pk[0]; po[1] = pk[1]; po[2] = pk[2];
        if (EPI == 2) {
            unsigned int* po2 = (unsigned int*)(out2 + o);
            po2[0] = pk[0]; po2[1] = pk[1]; po2[2] = pk[2];
        }
    }
}

// ---------------------------------------------------------------------------
// Per-node attention scalars: s[v] = h2[v]·a_s, d[v] = h2[v]·a_d (wave/node)
// ---------------------------------------------------------------------------
__global__ __launch_bounds__(256) void sd_k(
    const unsigned short* __restrict__ h2, const void* __restrict__ as_,
    const void* __restrict__ ad_, const int* __restrict__ dflag,
    float* __restrict__ s, float* __restrict__ d, int M)
{
    int f32 = dflag[0];
    int v = (blockIdx.x * blockDim.x + threadIdx.x) >> 6;
    int l = threadIdx.x & 63;
    if (v >= M) return;
    const unsigned short* r = h2 + (size_t)v * 96;
    float x1 = bf2f(r[l]);
    float x2 = (l < 32) ? bf2f(r[64 + l]) : 0.f;
    float as1 = ldf(as_, l, f32),  ad1 = ldf(ad_, l, f32);
    float as2 = (l < 32) ? ldf(as_, 64 + l, f32) : 0.f;
    float ad2 = (l < 32) ? ldf(ad_, 64 + l, f32) : 0.f;
    float ps = x1 * as1 + x2 * as2;
    float pd = x1 * ad1 + x2 * ad2;
    #pragma unroll
    for (int off = 32; off > 0; off >>= 1) {
        ps += __shfl_down(ps, off);
        pd += __shfl_down(pd, off);
    }
    if (l == 0) { s[v] = ps; d[v] = pd; }
}

// ---------------------------------------------------------------------------
// GAT aggregation, one wave per destination node over CSR (h2 bf16).
// Fast path (deg<=64): col + s gathered once into registers; softmax via
// shfl; feature gather 8-edge-batched — 8 independent shfls then 8
// independent 4B/lane loads in flight (breaks the serial shfl->load->fma
// chain that left the r6 version latency-bound at 66us, VALUBusy 25%).
// ---------------------------------------------------------------------------
__global__ __launch_bounds__(256) void agg_k(
    const unsigned short* __restrict__ h2, const float* __restrict__ s,
    const float* __restrict__ d, const int* __restrict__ rowptr,
    const unsigned short* __restrict__ col, const void* __restrict__ bias,
    const int* __restrict__ dflag, unsigned short* __restrict__ out, int M)
{
    int f32 = dflag[0];
    int v = (blockIdx.x * blockDim.x + threadIdx.x) >> 6;
    int l = threadIdx.x & 63;
    if (v >= M) return;
    int st = rowptr[v], en = rowptr[v + 1];
    int deg = en - st;
    float dv = d[v];

    if (deg > 0 && deg <= 64) {
        int u = 0; float e = -1e30f;
        if (l < deg) {
            u = col[st + l];
            float t = s[u] + dv;
            e = t >= 0.f ? t : 0.2f * t;
        }
        float lm = e;
        #pragma unroll
        for (int off = 32; off > 0; off >>= 1) lm = fmaxf(lm, __shfl_xor(lm, off));
        float w = (l < deg) ? __expf(e - lm) : 0.f;
        float ls = w;
        #pragma unroll
        for (int off = 32; off > 0; off >>= 1) ls += __shfl_xor(ls, off);
        float rden = 1.0f / ls;

        bool hw = (l < 48);
        int  c2 = 2 * l;
        float a0 = 0.f, a1 = 0.f;
        int j = 0;
        for (; j + 8 <= deg; j += 8) {
            int   u0 = __shfl(u, j + 0), u1 = __shfl(u, j + 1);
            int   u2 = __shfl(u, j + 2), u3 = __shfl(u, j + 3);
            int   u4 = __shfl(u, j + 4), u5 = __shfl(u, j + 5);
            int   u6 = __shfl(u, j + 6), u7 = __shfl(u, j + 7);
            float w0 = __shfl(w, j + 0), w1 = __shfl(w, j + 1);
            float w2 = __shfl(w, j + 2), w3 = __shfl(w, j + 3);
            float w4 = __shfl(w, j + 4), w5 = __shfl(w, j + 5);
            float w6 = __shfl(w, j + 6), w7 = __shfl(w, j + 7);
            if (hw) {
                unsigned int hv0 = *(const unsigned int*)(h2 + (size_t)u0 * 96 + c2);
                unsigned int hv1 = *(const unsigned int*)(h2 + (size_t)u1 * 96 + c2);
                unsigned int hv2 = *(const unsigned int*)(h2 + (size_t)u2 * 96 + c2);
                unsigned int hv3 = *(const unsigned int*)(h2 + (size_t)u3 * 96 + c2);
                unsigned int hv4 = *(const unsigned int*)(h2 + (size_t)u4 * 96 + c2);
                unsigned int hv5 = *(const unsigned int*)(h2 + (size_t)u5 * 96 + c2);
                unsigned int hv6 = *(const unsigned int*)(h2 + (size_t)u6 * 96 + c2);
                unsigned int hv7 = *(const unsigned int*)(h2 + (size_t)u7 * 96 + c2);
                a0 = fmaf(w0, bf2f(hv0 & 0xffff), a0); a1 = fmaf(w0, bf2f(hv0 >> 16), a1);
                a0 = fmaf(w1, bf2f(hv1 & 0xffff), a0); a1 = fmaf(w1, bf2f(hv1 >> 16), a1);
                a0 = fmaf(w2, bf2f(hv2 & 0xffff), a0); a1 = fmaf(w2, bf2f(hv2 >> 16), a1);
                a0 = fmaf(w3, bf2f(hv3 & 0xffff), a0); a1 = fmaf(w3, bf2f(hv3 >> 16), a1);
                a0 = fmaf(w4, bf2f(hv4 & 0xffff), a0); a1 = fmaf(w4, bf2f(hv4 >> 16), a1);
                a0 = fmaf(w5, bf2f(hv5 & 0xffff), a0); a1 = fmaf(w5, bf2f(hv5 >> 16), a1);
                a0 = fmaf(w6, bf2f(hv6 & 0xffff), a0); a1 = fmaf(w6, bf2f(hv6 >> 16), a1);
                a0 = fmaf(w7, bf2f(hv7 & 0xffff), a0); a1 = fmaf(w7, bf2f(hv7 >> 16), a1);
            }
        }
        for (; j < deg; j++) {
            int   uj = __shfl(u, j);
            float wj = __shfl(w, j);
            if (hw) {
                unsigned int hv = *(const unsigned int*)(h2 + (size_t)uj * 96 + c2);
                a0 = fmaf(wj, bf2f(hv & 0xffff), a0);
                a1 = fmaf(wj, bf2f(hv >> 16),    a1);
            }
        }
        if (hw) {
            float b0 = ldf(bias, c2,     f32);
            float b1 = ldf(bias, c2 + 1, f32);
            unsigned int o = (unsigned int)f2bf(a0 * rden + b0)
                           | ((unsigned int)f2bf(a1 * rden + b1) << 16);
            *(unsigned int*)(out + (size_t)v * 96 + c2) = o;
        }
        return;
    }

    // ---- general fallback (deg == 0 or deg > 64) ----
    int  c0 = l, c1 = 64 + l;
    bool has2 = (l < 32);
    if (deg <= 0) {
        out[(size_t)v * 96 + c0] = f2bf(ldf(bias, c0, f32));
        if (has2) out[(size_t)v * 96 + c1] = f2bf(ldf(bias, c1, f32));
        return;
    }
    float lm = -1e30f;
    for (int i = l; i < deg; i += 64) {
        float e = s[col[st + i]] + dv;
        e = e >= 0.f ? e : 0.2f * e;
        lm = fmaxf(lm, e);
    }
    #pragma unroll
    for (int off = 32; off > 0; off >>= 1) lm = fmaxf(lm, __shfl_xor(lm, off));
    float ls = 0.f;
    for (int i = l; i < deg; i += 64) {
        float e = s[col[st + i]] + dv;
        e = e >= 0.f ? e : 0.2f * e;
        ls += __expf(e - lm);
    }
    #pragma unroll
    for (int off = 32; off > 0; off >>= 1) ls += __shfl_xor(ls, off);
    float rden = 1.0f / ls;
    float acc0 = 0.f, acc1 = 0.f;
    for (int base = 0; base < deg; base += 64) {
        int i = base + l;
        int u = 0; float w = 0.f;
        if (i < deg) {
            u = col[st + i];
            float e = s[u] + dv;
            e = e >= 0.f ? e : 0.2f * e;
            w = __expf(e - lm);
        }
        int cl = min(64, deg - base);
        for (int j = 0; j < cl; j++) {
            int   uj = __shfl(u, j);
            float wj = __shfl(w, j);
            const unsigned short* hr = h2 + (size_t)uj * 96;
            acc0 = fmaf(wj, bf2f(hr[c0]), acc0);
            if (has2) acc1 = fmaf(wj, bf2f(hr[c1]), acc1);
        }
    }
    out[(size_t)v * 96 + c0] = f2bf(acc0 * rden + ldf(bias, c0, f32));
    if (has2) out[(size_t)v * 96 + c1] = f2bf(acc1 * rden + ldf(bias, c1, f32));
}

// ---------------------------------------------------------------------------
// BatchNorm statistics / coefficients / apply(+residual+lrelu)
// ---------------------------------------------------------------------------
__global__ __launch_bounds__(192) void bnstats_k(const unsigned short* __restrict__ x,
                                                 float* __restrict__ sums, int M)
{
    int c  = threadIdx.x % 96;
    int g2 = threadIdx.x / 96;
    float s = 0.f, q = 0.f;
    for (int r = blockIdx.x * 2 + g2; r < M; r += gridDim.x * 2) {
        float v = bf2f(x[(size_t)r * 96 + c]);
        s += v; q += v * v;
    }
    __shared__ float lsd[192], lqd[192];
    lsd[threadIdx.x] = s; lqd[threadIdx.x] = q;
    __syncthreads();
    if (g2 == 0) {
        atomicAdd(&sums[c],      s + lsd[threadIdx.x + 96]);
        atomicAdd(&sums[96 + c], q + lqd[threadIdx.x + 96]);
    }
}

__global__ void bncoef_k(const float* __restrict__ sums,
                         const void* __restrict__ g_,
                         const void* __restrict__ b_,
                         const int* __restrict__ dflag,
                         float* __restrict__ coef)
{
    int c = threadIdx.x;
    if (c >= 96) return;
    int f32 = dflag[0];
    float mu  = sums[c] * (1.f / N_NODES);
    float var = sums[96 + c] * (1.f / N_NODES) - mu * mu;
    float rinv = 1.0f / sqrtf(var + BN_EPS);
    float sc = ldf(g_, c, f32) * rinv;
    coef[c]      = sc;
    coef[96 + c] = ldf(b_, c, f32) - mu * sc;
}

// x/out may alias (in-place): no __restrict__ on those.
__global__ __launch_bounds__(256) void bnapply_k(const unsigned short* x,
                                                 const float* __restrict__ coef,
                                                 const unsigned short* __restrict__ iden,
                                                 unsigned short* out, int n4)
{
    int i = blockIdx.x * blockDim.x + threadIdx.x;
    if (i >= n4) return;
    int c4 = (i % 24) * 4;
    uint2 xu = ((const uint2*)x)[i];
    uint2 iu = ((const uint2*)iden)[i];
    float4 sc = *(const float4*)&coef[c4];
    float4 sh = *(const float4*)&coef[96 + c4];
    float r0 = lrelu01(bf2f(xu.x & 0xffff) * sc.x + sh.x) + bf2f(iu.x & 0xffff);
    float r1 = lrelu01(bf2f(xu.x >> 16)    * sc.y + sh.y) + bf2f(iu.x >> 16);
    float r2 = lrelu01(bf2f(xu.y & 0xffff) * sc.z + sh.z) + bf2f(iu.y & 0xffff);
    float r3 = lrelu01(bf2f(xu.y >> 16)    * sc.w + sh.w) + bf2f(iu.y >> 16);
    uint2 ou;
    ou.x = (unsigned int)f2bf(r0) | ((unsigned int)f2bf(r1) << 16);
    ou.y = (unsigned int)f2bf(r2) | ((unsigned int)f2bf(r3) << 16);
    ((uint2*)out)[i] = ou;
}

// ---------------------------------------------------------------------------
// Poincare expmap0 factor per node (wave/node)
// ---------------------------------------------------------------------------
__global__ __launch_bounds__(256) void pfac_k(const unsigned short* __restrict__ h,
                                              float* __restrict__ f, int M)
{
    int v = (blockIdx.x * blockDim.x + threadIdx.x) >> 6;
    int l = threadIdx.x & 63;
    if (v >= M) return;
    const unsigned short* r = h + (size_t)v * 96;
    float x1 = bf2f(r[l]);
    float x2 = (l < 32) ? bf2f(r[64 + l]) : 0.f;
    float q = x1 * x1 + x2 * x2;
    #pragma unroll
    for (int off = 32; off > 0; off >>= 1) q += __shfl_down(q, off);
    if (l == 0) {
        float n = fmaxf(sqrtf(q), 1e-15f);
        f[v] = tanhf(n) / n;
    }
}

// ---------------------------------------------------------------------------
// Graph mean-pool: register-accumulate per thread, flush on graph change.
// ---------------------------------------------------------------------------
__global__ __launch_bounds__(192) void pool_k(const unsigned short* __restrict__ h,
                                              const float* __restrict__ f,
                                              const int* __restrict__ batch,
                                              float* __restrict__ pooled,
                                              float* __restrict__ gcnt, int M)
{
    int c    = threadIdx.x % 96;
    int half = threadIdx.x / 96;
    int base = blockIdx.x * 64;
    int rend = min(base + 64, M);
    float acc = 0.f, cnt = 0.f;
    int curg = -1;
    for (int r = base + half; r < rend; r += 2) {
        int g = batch[r];
        if (g != curg) {
            if (curg >= 0) {
                atomicAdd(&pooled[curg * 96 + c], acc);
                if (c == 0) atomicAdd(&gcnt[curg], cnt);
            }
            acc = 0.f; cnt = 0.f; curg = g;
        }
        acc = fmaf(bf2f(h[(size_t)r * 96 + c]), f[r], acc);
        cnt += 1.f;
    }
    if (curg >= 0) {
        atomicAdd(&pooled[curg * 96 + c], acc);
        if (c == 0) atomicAdd(&gcnt[curg], cnt);
    }
}

// ---------------------------------------------------------------------------
// Head: one block per graph. pooled/cnt -> fc3+lrelu -> fc4 -> out.
// ---------------------------------------------------------------------------
__global__ __launch_bounds__(64) void head_k(const float* __restrict__ pooled,
                                             const float* __restrict__ gcnt,
                                             const void* __restrict__ w3,
                                             const void* __restrict__ b3,
                                             const void* __restrict__ w4,
                                             const void* __restrict__ b4,
                                             const int* __restrict__ dflag,
                                             void* __restrict__ outv)
{
    int g = blockIdx.x;
    int t = threadIdx.x;
    int f32 = dflag[0];
    __shared__ float p[96];
    __shared__ float o[48];
    float inv = 1.0f / fmaxf(gcnt[g], 1.0f);
    for (int c = t; c < 96; c += 64) p[c] = pooled[g * 96 + c] * inv;
    __syncthreads();
    if (t < 48) {
        float a = ldf(b3, t, f32);
        #pragma unroll
        for (int c = 0; c < 96; c++) a = fmaf(p[c], ldf(w3, (size_t)c * 48 + t, f32), a);
        o[t] = lrelu01(a);
    }
    __syncthreads();
    if (t < 4) {
        float a = ldf(b4, t, f32);
        #pragma unroll
        for (int j = 0; j < 48; j++) a = fmaf(o[j], ldf(w4, j * 4 + t, f32), a);
        if (f32) ((float*)outv)[g * 4 + t] = a;
        else     ((unsigned short*)outv)[g * 4 + t] = f2bf(a);
    }
}

// ---------------------------------------------------------------------------
// CSR construction (col stored as uint16 — node ids < 65536)
// ---------------------------------------------------------------------------
__global__ __launch_bounds__(256) void count_k(const int* __restrict__ ei,
                                               int* __restrict__ cnt)
{
    int e = blockIdx.x * 256 + threadIdx.x;
    if (e >= ET) return;
    int dstv = (e < N_EDGES) ? ei[N_EDGES + e] : (e - N_EDGES);
    atomicAdd(&cnt[dstv], 1);
}

__global__ __launch_bounds__(1024) void scan1_k(const int* __restrict__ cnt,
                                                int* __restrict__ rp,
                                                int* __restrict__ bsum, int n)
{
    __shared__ int sd[1024];
    int i = blockIdx.x * 1024 + threadIdx.x;
    int v = (i < n) ? cnt[i] : 0;
    sd[threadIdx.x] = v;
    __syncthreads();
    for (int off = 1; off < 1024; off <<= 1) {
        int t = 0;
        if (threadIdx.x >= off) t = sd[threadIdx.x - off];
        __syncthreads();
        if (threadIdx.x >= off) sd[threadIdx.x] += t;
        __syncthreads();
    }
    if (i < n) rp[i + 1] = sd[threadIdx.x];
    if (threadIdx.x == 1023) bsum[blockIdx.x] = sd[1023];
}

__global__ void scan2_k(int* __restrict__ bsum, int nb)
{
    if (blockIdx.x == 0 && threadIdx.x == 0) {
        int s = 0;
        for (int i = 0; i < nb; i++) { int t = bsum[i]; bsum[i] = s; s += t; }
    }
}

__global__ __launch_bounds__(1024) void scan3_k(int* __restrict__ rp,
                                                const int* __restrict__ bsum, int n)
{
    int i = blockIdx.x * 1024 + threadIdx.x;
    if (i < n) rp[i + 1] += bsum[blockIdx.x];
    if (i == 0) rp[0] = 0;
}

__global__ __launch_bounds__(256) void scatter_k(const int* __restrict__ ei,
                                                 const int* __restrict__ rp,
                                                 int* __restrict__ fill,
                                                 unsigned short* __restrict__ col)
{
    int e = blockIdx.x * 256 + threadIdx.x;
    if (e >= ET) return;
    int srcv, dstv;
    if (e < N_EDGES) { srcv = ei[e]; dstv = ei[N_EDGES + e]; }
    else             { srcv = dstv = e - N_EDGES; }
    int p = rp[dstv] + atomicAdd(&fill[dstv], 1);
    col[p] = (unsigned short)srcv;
}

// ---------------------------------------------------------------------------
extern "C" void kernel_launch(void* const* d_in, const int* in_sizes, int n_in,
                              void* d_out, int out_size, void* d_ws, size_t ws_size,
                              hipStream_t stream)
{
    const void* x     = d_in[0];
    const int*  ei    = (const int*)d_in[1];
    const int*  batch = (const int*)d_in[2];
    const void* embW  = d_in[3];
    const void* embB  = d_in[4];
    const void* convW[3]  = { d_in[5],  d_in[9],  d_in[13] };
    const void* convAs[3] = { d_in[6],  d_in[10], d_in[14] };
    const void* convAd[3] = { d_in[7],  d_in[11], d_in[15] };
    const void* convB[3]  = { d_in[8],  d_in[12], d_in[16] };
    const void* fcW[2]    = { d_in[17], d_in[19] };
    const void* fcB[2]    = { d_in[18], d_in[20] };
    const void* bnG[3]    = { d_in[21], d_in[23], d_in[25] };
    const void* bnB[3]    = { d_in[22], d_in[24], d_in[26] };
    const void* fc3W = d_in[27];
    const void* fc3b = d_in[28];
    const void* fc4W = d_in[29];
    const void* fc4b = d_in[30];

    // ---- workspace layout (total ≈ 31.5 MiB) ----
    char* wp_ = (char*)d_ws;
    auto alloc = [&](size_t b) { char* p = wp_; wp_ += (b + 255) & ~(size_t)255; return p; };
    int*   dflag = (int*)alloc(256);
    unsigned short* ident = (unsigned short*)alloc((size_t)N_NODES * H * 2);
    unsigned short* hA    = (unsigned short*)alloc((size_t)N_NODES * H * 2);
    unsigned short* hB    = (unsigned short*)alloc((size_t)N_NODES * H * 2);
    float* s_sc  = (float*)alloc((size_t)N_NODES * 4);
    float* d_sc  = (float*)alloc((size_t)N_NODES * 4);
    float* fvec  = (float*)alloc((size_t)N_NODES * 4);
    float* bnsum = (float*)alloc(192 * 4);
    float* coef  = (float*)alloc(192 * 4);
    float* pooled= (float*)alloc((NG * H + NG) * 4);
    float* gcnt  = pooled + NG * H;
    int*   rowptr= (int*)alloc((size_t)(N_NODES + 1) * 4);
    int*   cnt   = (int*)alloc((size_t)N_NODES * 4);
    unsigned short* col = (unsigned short*)alloc((size_t)ET * 2);
    int*   bsum  = (int*)alloc(64 * 4);

    const int NB = (N_NODES + 1023) / 1024;      // 49 scan blocks
    const int GE = (ET + 255) / 256;             // edge-parallel grid
    const int GM = (N_NODES + 63) / 64;          // gemm grid
    const int GW = (N_NODES * 64 + 255) / 256;   // wave-per-node grid
    const int N4 = N_NODES * H / 4;

    // ---- dtype detect ----
    detect_k<<<1, 64, 0, stream>>>((const unsigned short*)x, dflag);

    // ---- CSR build ----
    hipMemsetAsync(cnt, 0, (size_t)N_NODES * 4, stream);
    count_k<<<GE, 256, 0, stream>>>(ei, cnt);
    scan1_k<<<NB, 1024, 0, stream>>>(cnt, rowptr, bsum, N_NODES);
    scan2_k<<<1, 64, 0, stream>>>(bsum, NB);
    scan3_k<<<NB, 1024, 0, stream>>>(rowptr, bsum, N_NODES);
    hipMemsetAsync(cnt, 0, (size_t)N_NODES * 4, stream);
    scatter_k<<<GE, 256, 0, stream>>>(ei, rowptr, cnt, col);

    // ---- embed: h = lrelu(x @ embW + embB), identity = h ----
    gemm_k<2, 0><<<GM, 256, 0, stream>>>(x, embW, embB, dflag, hA, ident, N_NODES, F_IN);

    unsigned short* hcur = hA;
    unsigned short* htmp = hB;

    for (int l = 0; l < 3; l++) {
        // h2 = h @ convW
        gemm_k<0, 1><<<GM, 256, 0, stream>>>(hcur, convW[l], nullptr, dflag, htmp, nullptr, N_NODES, H);
        sd_k<<<GW, 256, 0, stream>>>(htmp, convAs[l], convAd[l], dflag, s_sc, d_sc, N_NODES);
        agg_k<<<GW, 256, 0, stream>>>(htmp, s_sc, d_sc, rowptr, col, convB[l], dflag, hcur, N_NODES);
        // BN + lrelu + residual
        hipMemsetAsync(bnsum, 0, 192 * 4, stream);
        bnstats_k<<<256, 192, 0, stream>>>(hcur, bnsum, N_NODES);
        bncoef_k<<<1, 128, 0, stream>>>(bnsum, bnG[l], bnB[l], dflag, coef);
        bnapply_k<<<(N4 + 255) / 256, 256, 0, stream>>>(hcur, coef, ident, hcur, N4);
        if (l < 2) {
            gemm_k<1, 1><<<GM, 256, 0, stream>>>(hcur, fcW[l], fcB[l], dflag, htmp, nullptr, N_NODES, H);
            unsigned short* t = hcur; hcur = htmp; htmp = t;
        }
    }

    // ---- Poincare + pooling + head ----
    pfac_k<<<GW, 256, 0, stream>>>(hcur, fvec, N_NODES);
    hipMemsetAsync(pooled, 0, (size_t)(NG * H + NG) * 4, stream);
    pool_k<<<(N_NODES + 63) / 64, 192, 0, stream>>>(hcur, fvec, batch, pooled, gcnt, N_NODES);
    head_k<<<NG, 64, 0, stream>>>(pooled, gcnt, fc3W, fc3b, fc4W, fc4b, dflag, d_out);
}

// Round 8
// 615.792 us; speedup vs baseline: 2.0678x; 1.1453x over previous
//
#include <hip/hip_runtime.h>
#include <hip/hip_bf16.h>

#define DEVINL __device__ __forceinline__

constexpr int N_NODES = 50000;
constexpr int N_EDGES = 800000;
constexpr int ET      = N_EDGES + N_NODES;   // edges + self loops
constexpr int F_IN    = 256;
constexpr int H       = 96;
constexpr int NG      = 64;                  // graphs
constexpr float BN_EPS = 1e-5f;

typedef short bf16x8 __attribute__((ext_vector_type(8)));
typedef float f32x4  __attribute__((ext_vector_type(4)));

DEVINL float bf2f(unsigned int u) {
    union { unsigned int i; float f; } c; c.i = u << 16; return c.f;
}
DEVINL unsigned short f2bf(float f) {
    union { float f; unsigned int i; } c; c.f = f;
    unsigned int x = c.i;
    return (unsigned short)((x + 0x7fffu + ((x >> 16) & 1u)) >> 16);
}
DEVINL float lrelu01(float v) { return v >= 0.f ? v : 0.01f * v; }
// dtype-flag aware scalar load of a "float tensor" input
DEVINL float ldf(const void* p, size_t i, int f32) {
    return f32 ? ((const float*)p)[i] : bf2f(((const unsigned short*)p)[i]);
}

// ---------------------------------------------------------------------------
// dtype detection: interpret first 64 shorts of x as bf16. fp32-backed data
// has random mantissa shorts -> many |v|>1e4/NaN. bf16-backed -> none.
// ---------------------------------------------------------------------------
__global__ void detect_k(const unsigned short* __restrict__ x, int* __restrict__ flag)
{
    int l = threadIdx.x;
    float f = bf2f(x[l]);
    bool huge = !(fabsf(f) <= 1e4f);          // catches NaN/Inf too
    unsigned long long m = __ballot(huge);
    if (l == 0) flag[0] = (__popcll(m) >= 8) ? 1 : 0;   // 1 = fp32, 0 = bf16
}

// ---------------------------------------------------------------------------
// Repack W[K,96] into MFMA B-fragment order for 16x16x32 bf16:
// dst[[chunk c][tile t][lane l][j]] = W[c*32 + (l>>4)*8 + j][t*16 + (l&15)]
// One thread per element; K*96 elements. Makes the GEMM B-load one coalesced
// 16B/lane global load (1KB/wave/instruction).
// ---------------------------------------------------------------------------
__global__ __launch_bounds__(256) void wpack_k(const void* __restrict__ src,
                                               const int* __restrict__ dflag,
                                               unsigned short* __restrict__ dst, int K)
{
    int i = blockIdx.x * 256 + threadIdx.x;
    if (i >= K * 96) return;
    int c   = i / 3072;
    int rem = i - c * 3072;
    int t    = rem >> 9;
    int rem2 = rem & 511;
    int l = rem2 >> 3, j = rem2 & 7;
    int k = c * 32 + (l >> 4) * 8 + j;
    int n = t * 16 + (l & 15);
    if (dflag[0]) dst[i] = f2bf(((const float*)src)[k * 96 + n]);
    else          dst[i] = ((const unsigned short*)src)[k * 96 + n];
}

// ---------------------------------------------------------------------------
// MFMA GEMM: out[M,96] = A[M,K] @ W[K,96], v_mfma_f32_16x16x32_bf16.
// Wave owns 16 rows x 96 cols (6 tiles, 6x f32x4 acc). No LDS, no barriers.
// A-frag: lane l -> A[row0+(l&15)][c*32+(l>>4)*8 + j] (16B load; lanes
// {l,l+16,l+32,l+48} cover one 64B row segment -> coalesced).
// B-frag: from wpack_k buffer, lane-contiguous 16B.
// D: col=lane&15, row=(lane>>4)*4+reg  [HW-verified m89/m91].
// EPI: 0 plain, 1 lrelu(acc+bias), 2 lrelu(acc+bias) -> out and out2
// AWS: 1 if A is workspace bf16, 0 if A is an input (dtype per dflag)
// ---------------------------------------------------------------------------
template<int EPI, int AWS>
__global__ __launch_bounds__(256) void mgemm_k(
    const void* __restrict__ Ap, const unsigned short* __restrict__ Wpk,
    const void* __restrict__ bp, const int* __restrict__ dflag,
    unsigned short* __restrict__ out, unsigned short* __restrict__ out2,
    int M, int K)
{
    const int f32  = AWS ? 0 : dflag[0];
    const int wf32 = dflag[0];
    const int l    = threadIdx.x & 63;
    const int wave = threadIdx.x >> 6;
    const int row0 = blockIdx.x * 64 + wave * 16;
    const int m    = l & 15;
    const int q    = l >> 4;
    const int arow = row0 + m;
    const bool aok = arow < M;

    f32x4 acc[6] = {};
    const int nch = K >> 5;
    const bf16x8* wp = (const bf16x8*)Wpk;

    for (int c = 0; c < nch; c++) {
        bf16x8 a = {};
        if (aok) {
            if (f32) {
                const float* A = (const float*)Ap + (size_t)arow * K + c * 32 + q * 8;
                #pragma unroll
                for (int j = 0; j < 8; j++) a[j] = (short)f2bf(A[j]);
            } else {
                a = *(const bf16x8*)((const unsigned short*)Ap + (size_t)arow * K + c * 32 + q * 8);
            }
        }
        const int base = c * 384 + l;
        #pragma unroll
        for (int t = 0; t < 6; t++)
            acc[t] = __builtin_amdgcn_mfma_f32_16x16x32_bf16(a, wp[base + t * 64], acc[t], 0, 0, 0);
    }

    float bv[6];
    if (EPI > 0) {
        #pragma unroll
        for (int t = 0; t < 6; t++) bv[t] = ldf(bp, t * 16 + m, wf32);
    }
    #pragma unroll
    for (int r = 0; r < 4; r++) {
        int rr = row0 + q * 4 + r;
        if (rr >= M) continue;
        size_t o = (size_t)rr * 96 + m;
        #pragma unroll
        for (int t = 0; t < 6; t++) {
            float v = acc[t][r];
            if (EPI > 0) v = lrelu01(v + bv[t]);
            unsigned short s = f2bf(v);
            out[o + t * 16] = s;
            if (EPI == 2) out2[o + t * 16] = s;
        }
    }
}

// ---------------------------------------------------------------------------
// Per-node attention scalars: s[v] = h2[v]·a_s, d[v] = h2[v]·a_d (wave/node)
// ---------------------------------------------------------------------------
__global__ __launch_bounds__(256) void sd_k(
    const unsigned short* __restrict__ h2, const void* __restrict__ as_,
    const void* __restrict__ ad_, const int* __restrict__ dflag,
    float* __restrict__ s, float* __restrict__ d, int M)
{
    int f32 = dflag[0];
    int v = (blockIdx.x * blockDim.x + threadIdx.x) >> 6;
    int l = threadIdx.x & 63;
    if (v >= M) return;
    const unsigned short* r = h2 + (size_t)v * 96;
    float x1 = bf2f(r[l]);
    float x2 = (l < 32) ? bf2f(r[64 + l]) : 0.f;
    float as1 = ldf(as_, l, f32),  ad1 = ldf(ad_, l, f32);
    float as2 = (l < 32) ? ldf(as_, 64 + l, f32) : 0.f;
    float ad2 = (l < 32) ? ldf(ad_, 64 + l, f32) : 0.f;
    float ps = x1 * as1 + x2 * as2;
    float pd = x1 * ad1 + x2 * ad2;
    #pragma unroll
    for (int off = 32; off > 0; off >>= 1) {
        ps += __shfl_down(ps, off);
        pd += __shfl_down(pd, off);
    }
    if (l == 0) { s[v] = ps; d[v] = pd; }
}

// ---------------------------------------------------------------------------
// GAT aggregation, one wave per destination node over CSR (h2 bf16).
// Fast path (deg<=64): col + s gathered once into registers; softmax via
// shfl; feature gather 8-edge-batched (8 independent loads in flight).
// ---------------------------------------------------------------------------
__global__ __launch_bounds__(256) void agg_k(
    const unsigned short* __restrict__ h2, const float* __restrict__ s,
    const float* __restrict__ d, const int* __restrict__ rowptr,
    const unsigned short* __restrict__ col, const void* __restrict__ bias,
    const int* __restrict__ dflag, unsigned short* __restrict__ out, int M)
{
    int f32 = dflag[0];
    int v = (blockIdx.x * blockDim.x + threadIdx.x) >> 6;
    int l = threadIdx.x & 63;
    if (v >= M) return;
    int st = rowptr[v], en = rowptr[v + 1];
    int deg = en - st;
    float dv = d[v];

    if (deg > 0 && deg <= 64) {
        int u = 0; float e = -1e30f;
        if (l < deg) {
            u = col[st + l];
            float t = s[u] + dv;
            e = t >= 0.f ? t : 0.2f * t;
        }
        float lm = e;
        #pragma unroll
        for (int off = 32; off > 0; off >>= 1) lm = fmaxf(lm, __shfl_xor(lm, off));
        float w = (l < deg) ? __expf(e - lm) : 0.f;
        float ls = w;
        #pragma unroll
        for (int off = 32; off > 0; off >>= 1) ls += __shfl_xor(ls, off);
        float rden = 1.0f / ls;

        bool hw = (l < 48);
        int  c2 = 2 * l;
        float a0 = 0.f, a1 = 0.f;
        int j = 0;
        for (; j + 8 <= deg; j += 8) {
            int   u0 = __shfl(u, j + 0), u1 = __shfl(u, j + 1);
            int   u2 = __shfl(u, j + 2), u3 = __shfl(u, j + 3);
            int   u4 = __shfl(u, j + 4), u5 = __shfl(u, j + 5);
            int   u6 = __shfl(u, j + 6), u7 = __shfl(u, j + 7);
            float w0 = __shfl(w, j + 0), w1 = __shfl(w, j + 1);
            float w2 = __shfl(w, j + 2), w3 = __shfl(w, j + 3);
            float w4 = __shfl(w, j + 4), w5 = __shfl(w, j + 5);
            float w6 = __shfl(w, j + 6), w7 = __shfl(w, j + 7);
            if (hw) {
                unsigned int hv0 = *(const unsigned int*)(h2 + (size_t)u0 * 96 + c2);
                unsigned int hv1 = *(const unsigned int*)(h2 + (size_t)u1 * 96 + c2);
                unsigned int hv2 = *(const unsigned int*)(h2 + (size_t)u2 * 96 + c2);
                unsigned int hv3 = *(const unsigned int*)(h2 + (size_t)u3 * 96 + c2);
                unsigned int hv4 = *(const unsigned int*)(h2 + (size_t)u4 * 96 + c2);
                unsigned int hv5 = *(const unsigned int*)(h2 + (size_t)u5 * 96 + c2);
                unsigned int hv6 = *(const unsigned int*)(h2 + (size_t)u6 * 96 + c2);
                unsigned int hv7 = *(const unsigned int*)(h2 + (size_t)u7 * 96 + c2);
                a0 = fmaf(w0, bf2f(hv0 & 0xffff), a0); a1 = fmaf(w0, bf2f(hv0 >> 16), a1);
                a0 = fmaf(w1, bf2f(hv1 & 0xffff), a0); a1 = fmaf(w1, bf2f(hv1 >> 16), a1);
                a0 = fmaf(w2, bf2f(hv2 & 0xffff), a0); a1 = fmaf(w2, bf2f(hv2 >> 16), a1);
                a0 = fmaf(w3, bf2f(hv3 & 0xffff), a0); a1 = fmaf(w3, bf2f(hv3 >> 16), a1);
                a0 = fmaf(w4, bf2f(hv4 & 0xffff), a0); a1 = fmaf(w4, bf2f(hv4 >> 16), a1);
                a0 = fmaf(w5, bf2f(hv5 & 0xffff), a0); a1 = fmaf(w5, bf2f(hv5 >> 16), a1);
                a0 = fmaf(w6, bf2f(hv6 & 0xffff), a0); a1 = fmaf(w6, bf2f(hv6 >> 16), a1);
                a0 = fmaf(w7, bf2f(hv7 & 0xffff), a0); a1 = fmaf(w7, bf2f(hv7 >> 16), a1);
            }
        }
        for (; j < deg; j++) {
            int   uj = __shfl(u, j);
            float wj = __shfl(w, j);
            if (hw) {
                unsigned int hv = *(const unsigned int*)(h2 + (size_t)uj * 96 + c2);
                a0 = fmaf(wj, bf2f(hv & 0xffff), a0);
                a1 = fmaf(wj, bf2f(hv >> 16),    a1);
            }
        }
        if (hw) {
            float b0 = ldf(bias, c2,     f32);
            float b1 = ldf(bias, c2 + 1, f32);
            unsigned int o = (unsigned int)f2bf(a0 * rden + b0)
                           | ((unsigned int)f2bf(a1 * rden + b1) << 16);
            *(unsigned int*)(out + (size_t)v * 96 + c2) = o;
        }
        return;
    }

    // ---- general fallback (deg == 0 or deg > 64) ----
    int  c0 = l, c1 = 64 + l;
    bool has2 = (l < 32);
    if (deg <= 0) {
        out[(size_t)v * 96 + c0] = f2bf(ldf(bias, c0, f32));
        if (has2) out[(size_t)v * 96 + c1] = f2bf(ldf(bias, c1, f32));
        return;
    }
    float lm = -1e30f;
    for (int i = l; i < deg; i += 64) {
        float e = s[col[st + i]] + dv;
        e = e >= 0.f ? e : 0.2f * e;
        lm = fmaxf(lm, e);
    }
    #pragma unroll
    for (int off = 32; off > 0; off >>= 1) lm = fmaxf(lm, __shfl_xor(lm, off));
    float ls = 0.f;
    for (int i = l; i < deg; i += 64) {
        float e = s[col[st + i]] + dv;
        e = e >= 0.f ? e : 0.2f * e;
        ls += __expf(e - lm);
    }
    #pragma unroll
    for (int off = 32; off > 0; off >>= 1) ls += __shfl_xor(ls, off);
    float rden = 1.0f / ls;
    float acc0 = 0.f, acc1 = 0.f;
    for (int base = 0; base < deg; base += 64) {
        int i = base + l;
        int u = 0; float w = 0.f;
        if (i < deg) {
            u = col[st + i];
            float e = s[u] + dv;
            e = e >= 0.f ? e : 0.2f * e;
            w = __expf(e - lm);
        }
        int cl = min(64, deg - base);
        for (int j = 0; j < cl; j++) {
            int   uj = __shfl(u, j);
            float wj = __shfl(w, j);
            const unsigned short* hr = h2 + (size_t)uj * 96;
            acc0 = fmaf(wj, bf2f(hr[c0]), acc0);
            if (has2) acc1 = fmaf(wj, bf2f(hr[c1]), acc1);
        }
    }
    out[(size_t)v * 96 + c0] = f2bf(acc0 * rden + ldf(bias, c0, f32));
    if (has2) out[(size_t)v * 96 + c1] = f2bf(acc1 * rden + ldf(bias, c1, f32));
}

// ---------------------------------------------------------------------------
// BatchNorm statistics / coefficients / apply(+residual+lrelu)
// ---------------------------------------------------------------------------
__global__ __launch_bounds__(192) void bnstats_k(const unsigned short* __restrict__ x,
                                                 float* __restrict__ sums, int M)
{
    int c  = threadIdx.x % 96;
    int g2 = threadIdx.x / 96;
    float s = 0.f, q = 0.f;
    for (int r = blockIdx.x * 2 + g2; r < M; r += gridDim.x * 2) {
        float v = bf2f(x[(size_t)r * 96 + c]);
        s += v; q += v * v;
    }
    __shared__ float lsd[192], lqd[192];
    lsd[threadIdx.x] = s; lqd[threadIdx.x] = q;
    __syncthreads();
    if (g2 == 0) {
        atomicAdd(&sums[c],      s + lsd[threadIdx.x + 96]);
        atomicAdd(&sums[96 + c], q + lqd[threadIdx.x + 96]);
    }
}

__global__ void bncoef_k(const float* __restrict__ sums,
                         const void* __restrict__ g_,
                         const void* __restrict__ b_,
                         const int* __restrict__ dflag,
                         float* __restrict__ coef)
{
    int c = threadIdx.x;
    if (c >= 96) return;
    int f32 = dflag[0];
    float mu  = sums[c] * (1.f / N_NODES);
    float var = sums[96 + c] * (1.f / N_NODES) - mu * mu;
    float rinv = 1.0f / sqrtf(var + BN_EPS);
    float sc = ldf(g_, c, f32) * rinv;
    coef[c]      = sc;
    coef[96 + c] = ldf(b_, c, f32) - mu * sc;
}

// x/out may alias (in-place): no __restrict__ on those.
__global__ __launch_bounds__(256) void bnapply_k(const unsigned short* x,
                                                 const float* __restrict__ coef,
                                                 const unsigned short* __restrict__ iden,
                                                 unsigned short* out, int n4)
{
    int i = blockIdx.x * blockDim.x + threadIdx.x;
    if (i >= n4) return;
    int c4 = (i % 24) * 4;
    uint2 xu = ((const uint2*)x)[i];
    uint2 iu = ((const uint2*)iden)[i];
    float4 sc = *(const float4*)&coef[c4];
    float4 sh = *(const float4*)&coef[96 + c4];
    float r0 = lrelu01(bf2f(xu.x & 0xffff) * sc.x + sh.x) + bf2f(iu.x & 0xffff);
    float r1 = lrelu01(bf2f(xu.x >> 16)    * sc.y + sh.y) + bf2f(iu.x >> 16);
    float r2 = lrelu01(bf2f(xu.y & 0xffff) * sc.z + sh.z) + bf2f(iu.y & 0xffff);
    float r3 = lrelu01(bf2f(xu.y >> 16)    * sc.w + sh.w) + bf2f(iu.y >> 16);
    uint2 ou;
    ou.x = (unsigned int)f2bf(r0) | ((unsigned int)f2bf(r1) << 16);
    ou.y = (unsigned int)f2bf(r2) | ((unsigned int)f2bf(r3) << 16);
    ((uint2*)out)[i] = ou;
}

// ---------------------------------------------------------------------------
// Poincare expmap0 factor per node (wave/node)
// ---------------------------------------------------------------------------
__global__ __launch_bounds__(256) void pfac_k(const unsigned short* __restrict__ h,
                                              float* __restrict__ f, int M)
{
    int v = (blockIdx.x * blockDim.x + threadIdx.x) >> 6;
    int l = threadIdx.x & 63;
    if (v >= M) return;
    const unsigned short* r = h + (size_t)v * 96;
    float x1 = bf2f(r[l]);
    float x2 = (l < 32) ? bf2f(r[64 + l]) : 0.f;
    float q = x1 * x1 + x2 * x2;
    #pragma unroll
    for (int off = 32; off > 0; off >>= 1) q += __shfl_down(q, off);
    if (l == 0) {
        float n = fmaxf(sqrtf(q), 1e-15f);
        f[v] = tanhf(n) / n;
    }
}

// ---------------------------------------------------------------------------
// Graph mean-pool: register-accumulate per thread, flush on graph change.
// ---------------------------------------------------------------------------
__global__ __launch_bounds__(192) void pool_k(const unsigned short* __restrict__ h,
                                              const float* __restrict__ f,
                                              const int* __restrict__ batch,
                                              float* __restrict__ pooled,
                                              float* __restrict__ gcnt, int M)
{
    int c    = threadIdx.x % 96;
    int half = threadIdx.x / 96;
    int base = blockIdx.x * 64;
    int rend = min(base + 64, M);
    float acc = 0.f, cnt = 0.f;
    int curg = -1;
    for (int r = base + half; r < rend; r += 2) {
        int g = batch[r];
        if (g != curg) {
            if (curg >= 0) {
                atomicAdd(&pooled[curg * 96 + c], acc);
                if (c == 0) atomicAdd(&gcnt[curg], cnt);
            }
            acc = 0.f; cnt = 0.f; curg = g;
        }
        acc = fmaf(bf2f(h[(size_t)r * 96 + c]), f[r], acc);
        cnt += 1.f;
    }
    if (curg >= 0) {
        atomicAdd(&pooled[curg * 96 + c], acc);
        if (c == 0) atomicAdd(&gcnt[curg], cnt);
    }
}

// ---------------------------------------------------------------------------
// Head: one block per graph. pooled/cnt -> fc3+lrelu -> fc4 -> out.
// ---------------------------------------------------------------------------
__global__ __launch_bounds__(64) void head_k(const float* __restrict__ pooled,
                                             const float* __restrict__ gcnt,
                                             const void* __restrict__ w3,
                                             const void* __restrict__ b3,
                                             const void* __restrict__ w4,
                                             const void* __restrict__ b4,
                                             const int* __restrict__ dflag,
                                             void* __restrict__ outv)
{
    int g = blockIdx.x;
    int t = threadIdx.x;
    int f32 = dflag[0];
    __shared__ float p[96];
    __shared__ float o[48];
    float inv = 1.0f / fmaxf(gcnt[g], 1.0f);
    for (int c = t; c < 96; c += 64) p[c] = pooled[g * 96 + c] * inv;
    __syncthreads();
    if (t < 48) {
        float a = ldf(b3, t, f32);
        #pragma unroll
        for (int c = 0; c < 96; c++) a = fmaf(p[c], ldf(w3, (size_t)c * 48 + t, f32), a);
        o[t] = lrelu01(a);
    }
    __syncthreads();
    if (t < 4) {
        float a = ldf(b4, t, f32);
        #pragma unroll
        for (int j = 0; j < 48; j++) a = fmaf(o[j], ldf(w4, j * 4 + t, f32), a);
        if (f32) ((float*)outv)[g * 4 + t] = a;
        else     ((unsigned short*)outv)[g * 4 + t] = f2bf(a);
    }
}

// ---------------------------------------------------------------------------
// CSR construction (col stored as uint16 — node ids < 65536)
// ---------------------------------------------------------------------------
__global__ __launch_bounds__(256) void count_k(const int* __restrict__ ei,
                                               int* __restrict__ cnt)
{
    int e = blockIdx.x * 256 + threadIdx.x;
    if (e >= ET) return;
    int dstv = (e < N_EDGES) ? ei[N_EDGES + e] : (e - N_EDGES);
    atomicAdd(&cnt[dstv], 1);
}

__global__ __launch_bounds__(1024) void scan1_k(const int* __restrict__ cnt,
                                                int* __restrict__ rp,
                                                int* __restrict__ bsum, int n)
{
    __shared__ int sd[1024];
    int i = blockIdx.x * 1024 + threadIdx.x;
    int v = (i < n) ? cnt[i] : 0;
    sd[threadIdx.x] = v;
    __syncthreads();
    for (int off = 1; off < 1024; off <<= 1) {
        int t = 0;
        if (threadIdx.x >= off) t = sd[threadIdx.x - off];
        __syncthreads();
        if (threadIdx.x >= off) sd[threadIdx.x] += t;
        __syncthreads();
    }
    if (i < n) rp[i + 1] = sd[threadIdx.x];
    if (threadIdx.x == 1023) bsum[blockIdx.x] = sd[1023];
}

__global__ void scan2_k(int* __restrict__ bsum, int nb)
{
    if (blockIdx.x == 0 && threadIdx.x == 0) {
        int s = 0;
        for (int i = 0; i < nb; i++) { int t = bsum[i]; bsum[i] = s; s += t; }
    }
}

__global__ __launch_bounds__(1024) void scan3_k(int* __restrict__ rp,
                                                const int* __restrict__ bsum, int n)
{
    int i = blockIdx.x * 1024 + threadIdx.x;
    if (i < n) rp[i + 1] += bsum[blockIdx.x];
    if (i == 0) rp[0] = 0;
}

__global__ __launch_bounds__(256) void scatter_k(const int* __restrict__ ei,
                                                 const int* __restrict__ rp,
                                                 int* __restrict__ fill,
                                                 unsigned short* __restrict__ col)
{
    int e = blockIdx.x * 256 + threadIdx.x;
    if (e >= ET) return;
    int srcv, dstv;
    if (e < N_EDGES) { srcv = ei[e]; dstv = ei[N_EDGES + e]; }
    else             { srcv = dstv = e - N_EDGES; }
    int p = rp[dstv] + atomicAdd(&fill[dstv], 1);
    col[p] = (unsigned short)srcv;
}

// ---------------------------------------------------------------------------
extern "C" void kernel_launch(void* const* d_in, const int* in_sizes, int n_in,
                              void* d_out, int out_size, void* d_ws, size_t ws_size,
                              hipStream_t stream)
{
    const void* x     = d_in[0];
    const int*  ei    = (const int*)d_in[1];
    const int*  batch = (const int*)d_in[2];
    const void* embW  = d_in[3];
    const void* embB  = d_in[4];
    const void* convW[3]  = { d_in[5],  d_in[9],  d_in[13] };
    const void* convAs[3] = { d_in[6],  d_in[10], d_in[14] };
    const void* convAd[3] = { d_in[7],  d_in[11], d_in[15] };
    const void* convB[3]  = { d_in[8],  d_in[12], d_in[16] };
    const void* fcW[2]    = { d_in[17], d_in[19] };
    const void* fcB[2]    = { d_in[18], d_in[20] };
    const void* bnG[3]    = { d_in[21], d_in[23], d_in[25] };
    const void* bnB[3]    = { d_in[22], d_in[24], d_in[26] };
    const void* fc3W = d_in[27];
    const void* fc3b = d_in[28];
    const void* fc4W = d_in[29];
    const void* fc4b = d_in[30];

    // ---- workspace layout (total ≈ 31.7 MiB) ----
    char* wp_ = (char*)d_ws;
    auto alloc = [&](size_t b) { char* p = wp_; wp_ += (b + 255) & ~(size_t)255; return p; };
    int*   dflag = (int*)alloc(256);
    unsigned short* ident = (unsigned short*)alloc((size_t)N_NODES * H * 2);
    unsigned short* hA    = (unsigned short*)alloc((size_t)N_NODES * H * 2);
    unsigned short* hB    = (unsigned short*)alloc((size_t)N_NODES * H * 2);
    float* s_sc  = (float*)alloc((size_t)N_NODES * 4);
    float* d_sc  = (float*)alloc((size_t)N_NODES * 4);
    float* fvec  = (float*)alloc((size_t)N_NODES * 4);
    float* bnsum = (float*)alloc(192 * 4);
    float* coef  = (float*)alloc(192 * 4);
    float* pooled= (float*)alloc((NG * H + NG) * 4);
    float* gcnt  = pooled + NG * H;
    int*   rowptr= (int*)alloc((size_t)(N_NODES + 1) * 4);
    int*   cnt   = (int*)alloc((size_t)N_NODES * 4);
    unsigned short* col = (unsigned short*)alloc((size_t)ET * 2);
    int*   bsum  = (int*)alloc(64 * 4);
    // packed MFMA B-fragment weights: emb (256x96) + 5 x (96x96)
    unsigned short* wpkEmb = (unsigned short*)alloc((size_t)F_IN * 96 * 2);
    unsigned short* wpkS[5];
    for (int i = 0; i < 5; i++) wpkS[i] = (unsigned short*)alloc((size_t)H * 96 * 2);

    const int NB = (N_NODES + 1023) / 1024;      // 49 scan blocks
    const int GE = (ET + 255) / 256;             // edge-parallel grid
    const int GM = (N_NODES + 63) / 64;          // gemm grid (64 rows/block)
    const int GW = (N_NODES * 64 + 255) / 256;   // wave-per-node grid
    const int N4 = N_NODES * H / 4;

    // ---- dtype detect ----
    detect_k<<<1, 64, 0, stream>>>((const unsigned short*)x, dflag);

    // ---- pack weights into MFMA fragment order ----
    wpack_k<<<(F_IN * 96 + 255) / 256, 256, 0, stream>>>(embW, dflag, wpkEmb, F_IN);
    wpack_k<<<(H * 96 + 255) / 256, 256, 0, stream>>>(convW[0], dflag, wpkS[0], H);
    wpack_k<<<(H * 96 + 255) / 256, 256, 0, stream>>>(convW[1], dflag, wpkS[1], H);
    wpack_k<<<(H * 96 + 255) / 256, 256, 0, stream>>>(convW[2], dflag, wpkS[2], H);
    wpack_k<<<(H * 96 + 255) / 256, 256, 0, stream>>>(fcW[0],   dflag, wpkS[3], H);
    wpack_k<<<(H * 96 + 255) / 256, 256, 0, stream>>>(fcW[1],   dflag, wpkS[4], H);

    // ---- CSR build ----
    hipMemsetAsync(cnt, 0, (size_t)N_NODES * 4, stream);
    count_k<<<GE, 256, 0, stream>>>(ei, cnt);
    scan1_k<<<NB, 1024, 0, stream>>>(cnt, rowptr, bsum, N_NODES);
    scan2_k<<<1, 64, 0, stream>>>(bsum, NB);
    scan3_k<<<NB, 1024, 0, stream>>>(rowptr, bsum, N_NODES);
    hipMemsetAsync(cnt, 0, (size_t)N_NODES * 4, stream);
    scatter_k<<<GE, 256, 0, stream>>>(ei, rowptr, cnt, col);

    // ---- embed: h = lrelu(x @ embW + embB), identity = h ----
    mgemm_k<2, 0><<<GM, 256, 0, stream>>>(x, wpkEmb, embB, dflag, hA, ident, N_NODES, F_IN);

    unsigned short* hcur = hA;
    unsigned short* htmp = hB;

    for (int l = 0; l < 3; l++) {
        // h2 = h @ convW
        mgemm_k<0, 1><<<GM, 256, 0, stream>>>(hcur, wpkS[l], nullptr, dflag, htmp, nullptr, N_NODES, H);
        sd_k<<<GW, 256, 0, stream>>>(htmp, convAs[l], convAd[l], dflag, s_sc, d_sc, N_NODES);
        agg_k<<<GW, 256, 0, stream>>>(htmp, s_sc, d_sc, rowptr, col, convB[l], dflag, hcur, N_NODES);
        // BN + lrelu + residual
        hipMemsetAsync(bnsum, 0, 192 * 4, stream);
        bnstats_k<<<256, 192, 0, stream>>>(hcur, bnsum, N_NODES);
        bncoef_k<<<1, 128, 0, stream>>>(bnsum, bnG[l], bnB[l], dflag, coef);
        bnapply_k<<<(N4 + 255) / 256, 256, 0, stream>>>(hcur, coef, ident, hcur, N4);
        if (l < 2) {
            mgemm_k<1, 1><<<GM, 256, 0, stream>>>(hcur, wpkS[3 + l], fcB[l], dflag, htmp, nullptr, N_NODES, H);
            unsigned short* t = hcur; hcur = htmp; htmp = t;
        }
    }

    // ---- Poincare + pooling + head ----
    pfac_k<<<GW, 256, 0, stream>>>(hcur, fvec, N_NODES);
    hipMemsetAsync(pooled, 0, (size_t)(NG * H + NG) * 4, stream);
    pool_k<<<(N_NODES + 63) / 64, 192, 0, stream>>>(hcur, fvec, batch, pooled, gcnt, N_NODES);
    head_k<<<NG, 64, 0, stream>>>(pooled, gcnt, fc3W, fc3b, fc4W, fc4b, dflag, d_out);
}